// Round 1
// 485.239 us; speedup vs baseline: 1.0829x; 1.0829x over previous
//
#include <hip/hip_runtime.h>
#include <hip/hip_bf16.h>
#include <cstddef>
#include <cstdint>

#define IN_DIM 256
#define HID 128
#define OUT_DIM 40

#define CHUNK 8192      // edges per binscatter block (private staging region)
#define BIN_SHIFT 10    // 1024 nodes per bin
#define BIN_SIZE 1024
#define MAXB 128        // >= NBINS+1
#define GSPLIT 8        // blocks per bin for deg/col kernels

typedef __attribute__((ext_vector_type(8))) short short8;
typedef __attribute__((ext_vector_type(4))) float f32x4;
typedef __attribute__((ext_vector_type(2))) float f32x2;

__device__ inline short f2bf(float f) {
    __hip_bfloat16 b = __float2bfloat16(f);   // RNE
    return __builtin_bit_cast(short, b);
}
__device__ inline float bf2f(unsigned short u) {
    unsigned int v = (unsigned int)u << 16;
    return __builtin_bit_cast(float, v);
}
// feature permutation for h1/x1 storage: slot p holds feature (p>>3) + 16*(p&7).
__device__ inline int permf(int p) { return (p >> 3) + 16 * (p & 7); }

// ---------------- CSR build: chunk-private counting sort by dst/src bin ----------------
__global__ __launch_bounds__(256) void k_binscatter(const int* __restrict__ src, const int* __restrict__ dst,
                                                    uint32_t* __restrict__ stD, unsigned short* __restrict__ stS,
                                                    int* __restrict__ bboD, int* __restrict__ bboS,
                                                    int E, int NBINS) {
    __shared__ int hD[MAXB], hS[MAXB], cD[MAXB], cS[MAXB], sd[MAXB];
    int j = blockIdx.x, t = threadIdx.x;
    int base = j * CHUNK;
    int nE = min(CHUNK, E - base);
    int NB1 = NBINS + 1;
    for (int i = t; i < MAXB; i += 256) { hD[i] = 0; hS[i] = 0; }
    __syncthreads();
    for (int i = t; i < nE; i += 256) {
        atomicAdd(&hD[dst[base + i] >> BIN_SHIFT], 1);
        atomicAdd(&hS[src[base + i] >> BIN_SHIFT], 1);
    }
    __syncthreads();
    if (t < MAXB) sd[t] = hD[t];
    __syncthreads();
    for (int off = 1; off < MAXB; off <<= 1) {
        int x = 0;
        if (t < MAXB && t >= off) x = sd[t - off];
        __syncthreads();
        if (t < MAXB) sd[t] += x;
        __syncthreads();
    }
    if (t < MAXB) cD[t] = sd[t] - hD[t];
    if (t < NBINS) bboD[(size_t)j * NB1 + t] = sd[t] - hD[t];
    if (t == NBINS) bboD[(size_t)j * NB1 + NBINS] = nE;
    __syncthreads();
    if (t < MAXB) sd[t] = hS[t];
    __syncthreads();
    for (int off = 1; off < MAXB; off <<= 1) {
        int x = 0;
        if (t < MAXB && t >= off) x = sd[t - off];
        __syncthreads();
        if (t < MAXB) sd[t] += x;
        __syncthreads();
    }
    if (t < MAXB) cS[t] = sd[t] - hS[t];
    if (t < NBINS) bboS[(size_t)j * NB1 + t] = sd[t] - hS[t];
    if (t == NBINS) bboS[(size_t)j * NB1 + NBINS] = nE;
    __syncthreads();
    for (int i = t; i < nE; i += 256) {
        int s = src[base + i], d = dst[base + i];
        int pD = atomicAdd(&cD[d >> BIN_SHIFT], 1);
        stD[(size_t)base + pD] = ((uint32_t)(d & (BIN_SIZE - 1)) << 17) | (uint32_t)s;
        int pS = atomicAdd(&cS[s >> BIN_SHIFT], 1);
        stS[(size_t)base + pS] = (unsigned short)(s & (BIN_SIZE - 1));
    }
}

// dst-degree histogram; also persists each (bin,g) block's histogram so k_col can reuse it.
__global__ __launch_bounds__(256) void k_deg_dst(const uint32_t* __restrict__ stD, const int* __restrict__ bboD,
                                                 int* __restrict__ deg_in, int* __restrict__ hsave,
                                                 int N, int nchunk, int NBINS) {
    __shared__ int hist[BIN_SIZE];
    int b = blockIdx.x, g = blockIdx.y, t = threadIdx.x;
    int wv = t >> 6, lane = t & 63;
    int NB1 = NBINS + 1;
    for (int i = t; i < BIN_SIZE; i += 256) hist[i] = 0;
    __syncthreads();
    for (int j = g * 4 + wv; j < nchunk; j += GSPLIT * 4) {
        int s = bboD[(size_t)j * NB1 + b], e = bboD[(size_t)j * NB1 + b + 1];
        const uint32_t* seg = stD + (size_t)j * CHUNK;
        for (int i = s + lane; i < e; i += 64)
            atomicAdd(&hist[seg[i] >> 17], 1);
    }
    __syncthreads();
    int base = b << BIN_SHIFT;
    int* hp = hsave + ((size_t)(b * GSPLIT + g) << BIN_SHIFT);
    for (int i = t; i < BIN_SIZE; i += 256) {
        int v = hist[i];
        hp[i] = v;
        if (v) atomicAdd(&deg_in[base + i], v);
    }
}

__global__ __launch_bounds__(256) void k_deg_src(const unsigned short* __restrict__ stS, const int* __restrict__ bboS,
                                                 int* __restrict__ deg_out, int N, int nchunk, int NBINS) {
    __shared__ int hist[BIN_SIZE];
    int b = blockIdx.x, g = blockIdx.y, t = threadIdx.x;
    int wv = t >> 6, lane = t & 63;
    int NB1 = NBINS + 1;
    for (int i = t; i < BIN_SIZE; i += 256) hist[i] = 0;
    __syncthreads();
    for (int j = g * 4 + wv; j < nchunk; j += GSPLIT * 4) {
        int s = bboS[(size_t)j * NB1 + b], e = bboS[(size_t)j * NB1 + b + 1];
        const unsigned short* seg = stS + (size_t)j * CHUNK;
        for (int i = s + lane; i < e; i += 64)
            atomicAdd(&hist[seg[i]], 1);
    }
    __syncthreads();
    int base = b << BIN_SHIFT;
    for (int i = t; i < BIN_SIZE; i += 256) {
        int v = hist[i];
        if (v) atomicAdd(&deg_out[base + i], v);
    }
}

// col scatter: reuses the histogram saved by k_deg_dst (same chunk partition per (b,g)),
// so only ONE pass over stD remains here.
__global__ __launch_bounds__(256) void k_col(const uint32_t* __restrict__ stD, const int* __restrict__ bboD,
                                             const int* __restrict__ hsave, int* __restrict__ cursor,
                                             int* __restrict__ col, int N, int nchunk, int NBINS) {
    __shared__ int hist[BIN_SIZE];
    int b = blockIdx.x, g = blockIdx.y, t = threadIdx.x;
    int wv = t >> 6, lane = t & 63;
    int NB1 = NBINS + 1;
    int base = b << BIN_SHIFT;
    const int* hp = hsave + ((size_t)(b * GSPLIT + g) << BIN_SHIFT);
    for (int i = t; i < BIN_SIZE; i += 256) {
        int v = hp[i];
        hist[i] = v ? atomicAdd(&cursor[base + i], v) : 0;
    }
    __syncthreads();
    for (int j = g * 4 + wv; j < nchunk; j += GSPLIT * 4) {
        int s = bboD[(size_t)j * NB1 + b], e = bboD[(size_t)j * NB1 + b + 1];
        const uint32_t* seg = stD + (size_t)j * CHUNK;
        for (int i = s + lane; i < e; i += 64) {
            uint32_t v = seg[i];
            int pos = atomicAdd(&hist[v >> 17], 1);
            col[pos] = (int)(v & 0x1FFFFu);
        }
    }
}

__global__ __launch_bounds__(256) void k_scan1(const int* __restrict__ deg, int* __restrict__ out,
                                               int* __restrict__ bsum, float* __restrict__ rs_in, int n) {
    __shared__ int sd[256];
    int t = threadIdx.x, b = blockIdx.x;
    int base = b * 1024 + t * 4;
    int v0 = 0, v1 = 0, v2 = 0, v3 = 0;
    if (base + 0 < n) v0 = deg[base + 0];
    if (base + 1 < n) v1 = deg[base + 1];
    if (base + 2 < n) v2 = deg[base + 2];
    if (base + 3 < n) v3 = deg[base + 3];
    if (base + 0 < n) rs_in[base + 0] = rsqrtf((float)max(v0, 1));
    if (base + 1 < n) rs_in[base + 1] = rsqrtf((float)max(v1, 1));
    if (base + 2 < n) rs_in[base + 2] = rsqrtf((float)max(v2, 1));
    if (base + 3 < n) rs_in[base + 3] = rsqrtf((float)max(v3, 1));
    int ts = v0 + v1 + v2 + v3;
    sd[t] = ts;
    __syncthreads();
    for (int off = 1; off < 256; off <<= 1) {
        int x = 0;
        if (t >= off) x = sd[t - off];
        __syncthreads();
        sd[t] += x;
        __syncthreads();
    }
    int excl = sd[t] - ts;
    if (base + 0 < n) out[base + 0] = excl;
    if (base + 1 < n) out[base + 1] = excl + v0;
    if (base + 2 < n) out[base + 2] = excl + v0 + v1;
    if (base + 3 < n) out[base + 3] = excl + v0 + v1 + v2;
    if (t == 255) bsum[b] = sd[255];
}

__global__ __launch_bounds__(1024) void k_scan2(int* __restrict__ bsum, int nb) {
    __shared__ int sd[1024];
    int t = threadIdx.x;
    int v = (t < nb) ? bsum[t] : 0;
    sd[t] = v;
    __syncthreads();
    for (int off = 1; off < 1024; off <<= 1) {
        int x = 0;
        if (t >= off) x = sd[t - off];
        __syncthreads();
        sd[t] += x;
        __syncthreads();
    }
    if (t < nb) bsum[t] = sd[t] - v;   // exclusive
}

__global__ __launch_bounds__(256) void k_scan3(int* __restrict__ row_ptr, const int* __restrict__ bsum,
                                               int* __restrict__ cursor, const int* __restrict__ deg_out,
                                               float* __restrict__ rs_out, int n, int E) {
    int i = blockIdx.x * 256 + threadIdx.x;
    if (i < n) {
        int v = row_ptr[i] + bsum[i >> 10];
        row_ptr[i] = v;
        cursor[i] = v;
        rs_out[i] = rsqrtf((float)max(deg_out[i], 1));
    }
    if (i == 0) row_ptr[n] = E;
}

// ---------------- W1 repack (once): fp32 [256][128] -> bf16 fragments [nt][ks][lane][8] ----------------
__global__ __launch_bounds__(256) void k_wrepack(const float* __restrict__ B, short* __restrict__ Wg) {
    int u = blockIdx.x * 256 + threadIdx.x;   // 8192 float4 units
    int k = u >> 5;                           // 0..255
    int n0 = (u & 31) * 4;
    float4 v = *(const float4*)(B + (size_t)k * HID + n0);
    int ks = k >> 5, quad = (k >> 3) & 3, j = k & 7;
    float vv[4] = {v.x, v.y, v.z, v.w};
#pragma unroll
    for (int e = 0; e < 4; ++e) {
        int n = n0 + e;
        int nt = n >> 4;
        int ln = (n & 15) | (quad << 4);
        Wg[(((nt * 8 + ks) * 64) + ln) * 8 + j] = f2bf(vv[e]);
    }
}

// ---------------- W2 repack (once): fp32 [128][40] -> bf16 B-fragments for fused GEMM2 ----------------
// frag f = nt*4+ks (nt: 16-col tile of padded 48; ks: K-step of 32 over the 128 permuted x1 slots).
// lane ln holds B[k = ks*32 + (ln>>4)*8 + j][col = nt*16 + (ln&15)], k indexes x1 SLOTS (permuted feats).
// Also emits b1p (bias permuted into slot order).
__global__ __launch_bounds__(256) void k_w2repack(const float* __restrict__ W2, const float* __restrict__ b1,
                                                  short* __restrict__ Wg2, float* __restrict__ b1p) {
    int t = blockIdx.x * 256 + threadIdx.x;
    if (t < 3 * 4 * 64 * 8) {
        int f = t >> 9;              // 0..11
        int ln = (t >> 3) & 63;
        int j = t & 7;
        int nt = f >> 2, ks = f & 3;
        int q = ks * 32 + (ln >> 4) * 8 + j;     // x1 slot
        int c = nt * 16 + (ln & 15);             // output col (pad 40->48 with 0)
        float v = (c < OUT_DIM) ? W2[(size_t)permf(q) * OUT_DIM + c] : 0.f;
        Wg2[t] = f2bf(v);
    }
    if (t < HID) b1p[t] = b1[permf(t)];
}

// ---------------- GEMM1 (bf16 MFMA): h1f = fp8((h @ W1) * rs_out[row]), permuted columns ----------------
__global__ __launch_bounds__(256) void k_gemm1(const float* __restrict__ A, const short* __restrict__ Wg,
                                               const float* __restrict__ rs_out, uint32_t* __restrict__ h1f, int M) {
    __shared__ short As[64 * 264];            // [row][k], k-pitch 264 (33 KB)
    int t = threadIdx.x;
    int lane = t & 63, wv = t >> 6;
    int block_row = blockIdx.x * 64;
#pragma unroll
    for (int i = 0; i < 16; ++i) {
        int u = t + i * 256;                  // 4096 float4 units
        int row = u >> 6, kq = (u & 63) * 4;
        int gr = block_row + row;
        float4 v = {0.f, 0.f, 0.f, 0.f};
        if (gr < M) v = *(const float4*)(A + (size_t)gr * IN_DIM + kq);
        short4 sv = {f2bf(v.x), f2bf(v.y), f2bf(v.z), f2bf(v.w)};
        *(short4*)&As[row * 264 + kq] = sv;
    }
    __syncthreads();
    f32x4 acc[8] = {};
    int arow = (wv * 16 + (lane & 15)) * 264 + (lane >> 4) * 8;
#pragma unroll
    for (int ks = 0; ks < 8; ++ks) {
        short8 a = *(short8*)&As[arow + ks * 32];
#pragma unroll
        for (int nt = 0; nt < 8; ++nt) {
            short8 b = *(const short8*)&Wg[(((nt * 8 + ks) * 64) + lane) * 8];
            acc[nt] = __builtin_amdgcn_mfma_f32_16x16x32_bf16(a, b, acc[nt], 0, 0, 0);
        }
    }
    int quad = lane >> 4, cl = lane & 15;
#pragma unroll
    for (int r = 0; r < 4; ++r) {
        int gr = block_row + wv * 16 + quad * 4 + r;
        if (gr >= M) continue;
        float sc = rs_out[gr];
        int d0 = __builtin_amdgcn_cvt_pk_fp8_f32(acc[0][r] * sc, acc[1][r] * sc, 0, false);
        d0 = __builtin_amdgcn_cvt_pk_fp8_f32(acc[2][r] * sc, acc[3][r] * sc, d0, true);
        int d1 = __builtin_amdgcn_cvt_pk_fp8_f32(acc[4][r] * sc, acc[5][r] * sc, 0, false);
        d1 = __builtin_amdgcn_cvt_pk_fp8_f32(acc[6][r] * sc, acc[7][r] * sc, d1, true);
        uint2 dd = make_uint2((uint32_t)d0, (uint32_t)d1);
        *(uint2*)((char*)h1f + (size_t)gr * 128 + cl * 8) = dd;
    }
}

// ---------------- Fused SpMM1 + ReLU + GEMM2 ----------------
// Block = 256 threads = 4 waves, 16 nodes (wave wv owns nodes wv*4..wv*4+3 sequentially).
// Gather: 16 lanes/edge x uint2 (8B), 4 edge-groups -> only a 2-level xor reduce (8 accs).
// x1 rows parked in LDS (bf16, XOR-swizzled), then 12 MFMAs compute h2f = fp8((x1@W2)*rs_out).
__global__ __launch_bounds__(256) void k_spmm1f(const uint2* __restrict__ h1f2, const int* __restrict__ rp,
                                                const int* __restrict__ col, const float* __restrict__ rs_in,
                                                const float* __restrict__ rs_out, const float* __restrict__ b1p,
                                                const short* __restrict__ Wg2,
                                                unsigned char* __restrict__ h2f, int N) {
    __shared__ uint32_t x1s[16 * 64];   // 16 rows x 128 bf16 slots, 4 KB, 16B-granule XOR swizzle
    __shared__ uint32_t hs[160];        // 16 x 40 fp8 bytes staging
    int t = threadIdx.x;
    int wv = t >> 6, lane = t & 63;
    int grp = lane >> 4, ql = lane & 15;
    int w_base = blockIdx.x * 16;

    // preload W2 fragments for this wave's N-tile (wave 3 idles in MFMA phase) + permuted bias
    int ntl = (wv < 3) ? wv : 0;
    short8 wf0 = *(const short8*)&Wg2[((ntl * 4 + 0) * 64 + lane) * 8];
    short8 wf1 = *(const short8*)&Wg2[((ntl * 4 + 1) * 64 + lane) * 8];
    short8 wf2 = *(const short8*)&Wg2[((ntl * 4 + 2) * 64 + lane) * 8];
    short8 wf3 = *(const short8*)&Wg2[((ntl * 4 + 3) * 64 + lane) * 8];
    float4 blo = *(const float4*)&b1p[ql * 8];
    float4 bhi = *(const float4*)&b1p[ql * 8 + 4];

    for (int i = t; i < 16 * 64; i += 256) x1s[i] = 0;   // tail safety
    __syncthreads();

#pragma unroll 1
    for (int q = 0; q < 4; ++q) {
        int nloc = wv * 4 + q;
        int w = w_base + nloc;
        if (w < N) {
            int s = rp[w], e = rp[w + 1];
            float acc[8] = {};
            int i = s;
            while (i < e) {
                int cnt = min(64, e - i);
                int cl = (lane < cnt) ? lane : cnt - 1;
                int cidx = col[i + cl];
                for (int it = 0; it < cnt; it += 8) {
                    int eA = it + grp, eB = it + 4 + grp;     // eA<=59, eB<=63 always
                    int cA = __shfl(cidx, eA, 64);
                    int cB = __shfl(cidx, eB, 64);
                    float mA = (eA < cnt) ? 1.f : 0.f;
                    float mB = (eB < cnt) ? 1.f : 0.f;
                    uint2 uA = h1f2[(size_t)cA * 16 + ql];
                    uint2 uB = h1f2[(size_t)cB * 16 + ql];
                    {
                        f32x2 p0 = __builtin_amdgcn_cvt_pk_f32_fp8(uA.x, false);
                        f32x2 p1 = __builtin_amdgcn_cvt_pk_f32_fp8(uA.x, true);
                        f32x2 p2 = __builtin_amdgcn_cvt_pk_f32_fp8(uA.y, false);
                        f32x2 p3 = __builtin_amdgcn_cvt_pk_f32_fp8(uA.y, true);
                        acc[0] = fmaf(p0.x, mA, acc[0]); acc[1] = fmaf(p0.y, mA, acc[1]);
                        acc[2] = fmaf(p1.x, mA, acc[2]); acc[3] = fmaf(p1.y, mA, acc[3]);
                        acc[4] = fmaf(p2.x, mA, acc[4]); acc[5] = fmaf(p2.y, mA, acc[5]);
                        acc[6] = fmaf(p3.x, mA, acc[6]); acc[7] = fmaf(p3.y, mA, acc[7]);
                    }
                    {
                        f32x2 p0 = __builtin_amdgcn_cvt_pk_f32_fp8(uB.x, false);
                        f32x2 p1 = __builtin_amdgcn_cvt_pk_f32_fp8(uB.x, true);
                        f32x2 p2 = __builtin_amdgcn_cvt_pk_f32_fp8(uB.y, false);
                        f32x2 p3 = __builtin_amdgcn_cvt_pk_f32_fp8(uB.y, true);
                        acc[0] = fmaf(p0.x, mB, acc[0]); acc[1] = fmaf(p0.y, mB, acc[1]);
                        acc[2] = fmaf(p1.x, mB, acc[2]); acc[3] = fmaf(p1.y, mB, acc[3]);
                        acc[4] = fmaf(p2.x, mB, acc[4]); acc[5] = fmaf(p2.y, mB, acc[5]);
                        acc[6] = fmaf(p3.x, mB, acc[6]); acc[7] = fmaf(p3.y, mB, acc[7]);
                    }
                }
                i += cnt;
            }
            // fold the 4 edge-groups (lane bits 4,5)
#pragma unroll
            for (int j = 0; j < 8; ++j) {
                acc[j] += __shfl_xor(acc[j], 16, 64);
                acc[j] += __shfl_xor(acc[j], 32, 64);
            }
            if (lane < 16) {
                float sc = rs_in[w];
                float f0, f1;
                uint32_t o0, o1, o2, o3;
                f0 = fmaxf(fmaf(acc[0], sc, blo.x), 0.f); f1 = fmaxf(fmaf(acc[1], sc, blo.y), 0.f);
                o0 = (uint32_t)(unsigned short)f2bf(f0) | ((uint32_t)(unsigned short)f2bf(f1) << 16);
                f0 = fmaxf(fmaf(acc[2], sc, blo.z), 0.f); f1 = fmaxf(fmaf(acc[3], sc, blo.w), 0.f);
                o1 = (uint32_t)(unsigned short)f2bf(f0) | ((uint32_t)(unsigned short)f2bf(f1) << 16);
                f0 = fmaxf(fmaf(acc[4], sc, bhi.x), 0.f); f1 = fmaxf(fmaf(acc[5], sc, bhi.y), 0.f);
                o2 = (uint32_t)(unsigned short)f2bf(f0) | ((uint32_t)(unsigned short)f2bf(f1) << 16);
                f0 = fmaxf(fmaf(acc[6], sc, bhi.z), 0.f); f1 = fmaxf(fmaf(acc[7], sc, bhi.w), 0.f);
                o3 = (uint32_t)(unsigned short)f2bf(f0) | ((uint32_t)(unsigned short)f2bf(f1) << 16);
                int woff = (nloc * 256 + ql * 16) ^ ((nloc & 7) << 4);
                *(uint4*)((char*)x1s + woff) = make_uint4(o0, o1, o2, o3);
            }
        }
    }
    __syncthreads();
    int vr = min(16, N - w_base);
    if (wv < 3) {
        int row = lane & 15, kc = lane >> 4;
        int rbase = row * 256 + kc * 16;
        int swz = (row & 7) << 4;
        f32x4 c = {};
        c = __builtin_amdgcn_mfma_f32_16x16x32_bf16(*(short8*)((char*)x1s + ((rbase + 0) ^ swz)),   wf0, c, 0, 0, 0);
        c = __builtin_amdgcn_mfma_f32_16x16x32_bf16(*(short8*)((char*)x1s + ((rbase + 64) ^ swz)),  wf1, c, 0, 0, 0);
        c = __builtin_amdgcn_mfma_f32_16x16x32_bf16(*(short8*)((char*)x1s + ((rbase + 128) ^ swz)), wf2, c, 0, 0, 0);
        c = __builtin_amdgcn_mfma_f32_16x16x32_bf16(*(short8*)((char*)x1s + ((rbase + 192) ^ swz)), wf3, c, 0, 0, 0);
        int cc = wv * 16 + row;     // output column 0..47 (only <40 valid)
        int r0 = kc * 4;
        if (cc < OUT_DIM) {
#pragma unroll
            for (int r = 0; r < 4; ++r) {
                int node = r0 + r;
                if (node < vr) {
                    float v = c[r] * rs_out[w_base + node];
                    int pk = __builtin_amdgcn_cvt_pk_fp8_f32(v, v, 0, false);
                    ((unsigned char*)hs)[node * 40 + cc] = (unsigned char)(pk & 0xff);
                }
            }
        }
    }
    __syncthreads();
    uint32_t* dp = (uint32_t*)(h2f + (size_t)w_base * 40);
    for (int idx = t; idx < vr * 10; idx += 256) dp[idx] = hs[idx];
}

// ---------------- SpMM2 (fp8, MLP) + bias + log_softmax ----------------
// 5 lanes/edge x uint2 (40 B row); 12 edge-groups/wave; col batch-prefetch via shfl.
__global__ __launch_bounds__(256) void k_spmm2(const unsigned char* __restrict__ h2f, const int* __restrict__ rp,
                                               const int* __restrict__ col, const float* __restrict__ rs_in,
                                               const float* __restrict__ b2, float* __restrict__ out, int n) {
    int w = (blockIdx.x * 256 + threadIdx.x) >> 6;
    int lane = threadIdx.x & 63;
    if (w >= n) return;
    int grp = lane / 5;                  // 0..12 (grp 12 = lanes 60..63, inactive)
    int dw = lane - grp * 5;             // 0..4
    bool gval = grp < 12;
    int s = rp[w], e = rp[w + 1];
    float acc[8] = {};
    int i = s;
    while (i < e) {
        int cnt = min(64, e - i);
        int cl = (lane < cnt) ? lane : cnt - 1;
        int cidx = col[i + cl];
        for (int it = 0; it < cnt; it += 24) {
            int eA = it + grp, eB = it + 12 + grp;
            int cA = __shfl(cidx, eA & 63, 64);
            int cB = __shfl(cidx, eB & 63, 64);
            float mA = (gval && eA < cnt) ? 1.f : 0.f;
            float mB = (gval && eB < cnt) ? 1.f : 0.f;
            uint2 uA = *(const uint2*)(h2f + (size_t)cA * 40 + dw * 8);
            uint2 uB = *(const uint2*)(h2f + (size_t)cB * 40 + dw * 8);
            {
                f32x2 p0 = __builtin_amdgcn_cvt_pk_f32_fp8(uA.x, false);
                f32x2 p1 = __builtin_amdgcn_cvt_pk_f32_fp8(uA.x, true);
                f32x2 p2 = __builtin_amdgcn_cvt_pk_f32_fp8(uA.y, false);
                f32x2 p3 = __builtin_amdgcn_cvt_pk_f32_fp8(uA.y, true);
                acc[0] = fmaf(p0.x, mA, acc[0]); acc[1] = fmaf(p0.y, mA, acc[1]);
                acc[2] = fmaf(p1.x, mA, acc[2]); acc[3] = fmaf(p1.y, mA, acc[3]);
                acc[4] = fmaf(p2.x, mA, acc[4]); acc[5] = fmaf(p2.y, mA, acc[5]);
                acc[6] = fmaf(p3.x, mA, acc[6]); acc[7] = fmaf(p3.y, mA, acc[7]);
            }
            {
                f32x2 p0 = __builtin_amdgcn_cvt_pk_f32_fp8(uB.x, false);
                f32x2 p1 = __builtin_amdgcn_cvt_pk_f32_fp8(uB.x, true);
                f32x2 p2 = __builtin_amdgcn_cvt_pk_f32_fp8(uB.y, false);
                f32x2 p3 = __builtin_amdgcn_cvt_pk_f32_fp8(uB.y, true);
                acc[0] = fmaf(p0.x, mB, acc[0]); acc[1] = fmaf(p0.y, mB, acc[1]);
                acc[2] = fmaf(p1.x, mB, acc[2]); acc[3] = fmaf(p1.y, mB, acc[3]);
                acc[4] = fmaf(p2.x, mB, acc[4]); acc[5] = fmaf(p2.y, mB, acc[5]);
                acc[6] = fmaf(p3.x, mB, acc[6]); acc[7] = fmaf(p3.y, mB, acc[7]);
            }
        }
        i += cnt;
    }
    // fold 12 groups (stride 5) -> group 0 (lanes 0..4)
#pragma unroll
    for (int j = 0; j < 8; ++j) {
        acc[j] += __shfl(acc[j], (lane + 30) & 63, 64);
        acc[j] += __shfl(acc[j], (lane + 15) & 63, 64);
        acc[j] += __shfl(acc[j], (lane + 5) & 63, 64) + __shfl(acc[j], (lane + 10) & 63, 64);
    }
    bool act = lane < 5;
    float sc = rs_in[w];
    float val[8];
#pragma unroll
    for (int j = 0; j < 8; ++j)
        val[j] = fmaf(acc[j], sc, b2[dw * 8 + j]);
    float pm = -INFINITY;
    if (act) {
        pm = val[0];
#pragma unroll
        for (int j = 1; j < 8; ++j) pm = fmaxf(pm, val[j]);
    }
    pm = fmaxf(pm, __shfl_xor(pm, 4, 8));
    pm = fmaxf(pm, __shfl_xor(pm, 2, 8));
    pm = fmaxf(pm, __shfl_xor(pm, 1, 8));
    float ex = 0.f;
    if (act) {
#pragma unroll
        for (int j = 0; j < 8; ++j) ex += expf(val[j] - pm);
    }
    ex += __shfl_xor(ex, 4, 8);
    ex += __shfl_xor(ex, 2, 8);
    ex += __shfl_xor(ex, 1, 8);
    if (act) {
        float l = pm + logf(ex);
        float4 o0 = {val[0] - l, val[1] - l, val[2] - l, val[3] - l};
        float4 o1 = {val[4] - l, val[5] - l, val[6] - l, val[7] - l};
        float* op = out + (size_t)w * OUT_DIM + dw * 8;
        *(float4*)op = o0;
        *(float4*)(op + 4) = o1;
    }
}

// ---------------- launch ----------------

extern "C" void kernel_launch(void* const* d_in, const int* in_sizes, int n_in,
                              void* d_out, int out_size, void* d_ws, size_t ws_size,
                              hipStream_t stream) {
    const int N = in_sizes[0] / IN_DIM;
    const int E = in_sizes[5];
    const float* h  = (const float*)d_in[0];
    const float* W1 = (const float*)d_in[1];
    const float* b1 = (const float*)d_in[2];
    const float* W2 = (const float*)d_in[3];
    const float* b2 = (const float*)d_in[4];
    const int* src  = (const int*)d_in[5];
    const int* dst  = (const int*)d_in[6];
    float* out = (float*)d_out;

    const int NBINS  = (N + BIN_SIZE - 1) >> BIN_SHIFT;   // 98
    const int NCHUNK = (E + CHUNK - 1) / CHUNK;           // 391

    char* w = (char*)d_ws;
    size_t off = 0;
    auto alloc = [&](size_t bytes) -> void* {
        void* p = w + off;
        off += (bytes + 255) & ~(size_t)255;
        return p;
    };
    int* deg_in   = (int*)alloc((size_t)N * 4);
    int* deg_out  = (int*)alloc((size_t)N * 4);
    int* row_ptr  = (int*)alloc((size_t)(N + 1) * 4);
    int* cursor   = (int*)alloc((size_t)N * 4);
    int* bsum     = (int*)alloc(1024 * 4);
    float* rs_out = (float*)alloc((size_t)N * 4);
    float* rs_in  = (float*)alloc((size_t)N * 4);
    int* col      = (int*)alloc((size_t)E * 4);
    int* bboD     = (int*)alloc((size_t)NCHUNK * (NBINS + 1) * 4);
    int* bboS     = (int*)alloc((size_t)NCHUNK * (NBINS + 1) * 4);
    short* Wg     = (short*)alloc((size_t)8 * 8 * 64 * 8 * 2);    // 64 KB
    short* Wg2    = (short*)alloc((size_t)3 * 4 * 64 * 8 * 2);    // 12 KB
    float* b1p    = (float*)alloc((size_t)HID * 4);
    int* hsave    = (int*)alloc((size_t)NBINS * GSPLIT * BIN_SIZE * 4);   // 3.2 MB
    // staging regions; dead before their aliases are written (stream-ordered):
    //   stD read last by k_col, then k_gemm1 writes h1f over it.
    //   stS read last by k_deg_src, then k_spmm1f writes h2f over it.
    size_t stD_bytes = (size_t)E * 4;  if ((size_t)N * HID > stD_bytes) stD_bytes = (size_t)N * HID;
    size_t stS_bytes = (size_t)E * 2;  if ((size_t)N * OUT_DIM > stS_bytes) stS_bytes = (size_t)N * OUT_DIM;
    uint32_t* stD = (uint32_t*)alloc(stD_bytes);
    unsigned short* stS = (unsigned short*)alloc(stS_bytes);
    uint32_t* h1f = (uint32_t*)stD;                       // fp8 [N][128], 12.8 MB
    unsigned char* h2f = (unsigned char*)stS;             // fp8 [N][40], 4 MB

    int gN = (N + 255) / 256;
    int NB = (N + 1023) / 1024;

    hipMemsetAsync(deg_in, 0, (size_t)N * 4, stream);
    hipMemsetAsync(deg_out, 0, (size_t)N * 4, stream);
    k_wrepack<<<32, 256, 0, stream>>>(W1, Wg);
    k_w2repack<<<24, 256, 0, stream>>>(W2, b1, Wg2, b1p);
    k_binscatter<<<NCHUNK, 256, 0, stream>>>(src, dst, stD, stS, bboD, bboS, E, NBINS);
    k_deg_src<<<dim3(NBINS, GSPLIT), 256, 0, stream>>>(stS, bboS, deg_out, N, NCHUNK, NBINS);
    k_deg_dst<<<dim3(NBINS, GSPLIT), 256, 0, stream>>>(stD, bboD, deg_in, hsave, N, NCHUNK, NBINS);
    k_scan1<<<NB, 256, 0, stream>>>(deg_in, row_ptr, bsum, rs_in, N);
    k_scan2<<<1, 1024, 0, stream>>>(bsum, NB);
    k_scan3<<<gN, 256, 0, stream>>>(row_ptr, bsum, cursor, deg_out, rs_out, N, E);
    k_col<<<dim3(NBINS, GSPLIT), 256, 0, stream>>>(stD, bboD, hsave, cursor, col, N, NCHUNK, NBINS);
    k_gemm1<<<(N + 63) / 64, 256, 0, stream>>>(h, Wg, rs_out, h1f, N);
    k_spmm1f<<<(N + 15) / 16, 256, 0, stream>>>((const uint2*)h1f, row_ptr, col, rs_in, rs_out, b1p, Wg2, h2f, N);
    k_spmm2<<<(N + 3) / 4, 256, 0, stream>>>(h2f, row_ptr, col, rs_in, b2, out, N);
}

// Round 2
// 467.385 us; speedup vs baseline: 1.1243x; 1.0382x over previous
//
#include <hip/hip_runtime.h>
#include <hip/hip_bf16.h>
#include <cstddef>
#include <cstdint>

#define IN_DIM 256
#define HID 128
#define OUT_DIM 40

#define CHUNK 8192      // edges per binscatter block (private staging region)
#define BIN_SHIFT 10    // 1024 nodes per bin
#define BIN_SIZE 1024
#define MAXB 128        // >= NBINS+1
#define GSPLIT 8        // blocks per bin for deg/col kernels

typedef __attribute__((ext_vector_type(8))) short short8;
typedef __attribute__((ext_vector_type(4))) float f32x4;
typedef __attribute__((ext_vector_type(2))) float f32x2;

__device__ inline short f2bf(float f) {
    __hip_bfloat16 b = __float2bfloat16(f);   // RNE
    return __builtin_bit_cast(short, b);
}
__device__ inline float bf2f(unsigned short u) {
    unsigned int v = (unsigned int)u << 16;
    return __builtin_bit_cast(float, v);
}
// feature permutation for h1/x1 storage: slot p holds feature (p>>3) + 16*(p&7).
__device__ inline int permf(int p) { return (p >> 3) + 16 * (p & 7); }

// ---------------- setup: W1 repack + W2 repack + b1 permute + deg zeroing (one launch) ----------------
__global__ __launch_bounds__(256) void k_setup(const float* __restrict__ W1, const float* __restrict__ W2,
                                               const float* __restrict__ b1, short* __restrict__ Wg,
                                               short* __restrict__ Wg2, float* __restrict__ b1p,
                                               int* __restrict__ deg_in, int* __restrict__ deg_out, int Z) {
    int flat = blockIdx.x * 256 + threadIdx.x;
    if (flat < 8192) {                        // W1: fp32 [256][128] -> bf16 fragments [nt][ks][lane][8]
        int k = flat >> 5;                    // 0..255
        int n0 = (flat & 31) * 4;
        float4 v = *(const float4*)(W1 + (size_t)k * HID + n0);
        int ks = k >> 5, quad = (k >> 3) & 3, j = k & 7;
        float vv[4] = {v.x, v.y, v.z, v.w};
#pragma unroll
        for (int e = 0; e < 4; ++e) {
            int n = n0 + e;
            int nt = n >> 4;
            int ln = (n & 15) | (quad << 4);
            Wg[(((nt * 8 + ks) * 64) + ln) * 8 + j] = f2bf(vv[e]);
        }
        return;
    }
    flat -= 8192;
    if (flat < 3 * 4 * 64 * 8) {              // W2: fp32 [128][40] -> bf16 B-fragments (pad cols 40->48)
        int f = flat >> 9;                    // 0..11
        int ln = (flat >> 3) & 63;
        int j = flat & 7;
        int nt = f >> 2, ks = f & 3;
        int q = ks * 32 + (ln >> 4) * 8 + j;  // x1 slot (permuted feature index)
        int c = nt * 16 + (ln & 15);          // output col
        float v = (c < OUT_DIM) ? W2[(size_t)permf(q) * OUT_DIM + c] : 0.f;
        Wg2[flat] = f2bf(v);
        return;
    }
    flat -= 3 * 4 * 64 * 8;
    if (flat < HID) { b1p[flat] = b1[permf(flat)]; return; }
    flat -= HID;
    if (flat < Z) { *(int4*)(deg_in + flat * 4) = make_int4(0, 0, 0, 0); return; }
    flat -= Z;
    if (flat < Z) { *(int4*)(deg_out + flat * 4) = make_int4(0, 0, 0, 0); }
}

// ---------------- CSR build: chunk-private counting sort by dst/src bin ----------------
__global__ __launch_bounds__(256) void k_binscatter(const int* __restrict__ src, const int* __restrict__ dst,
                                                    uint32_t* __restrict__ stD, unsigned short* __restrict__ stS,
                                                    int* __restrict__ bboD, int* __restrict__ bboS,
                                                    int E, int NBINS) {
    __shared__ int hD[MAXB], hS[MAXB], cD[MAXB], cS[MAXB], sd[MAXB];
    int j = blockIdx.x, t = threadIdx.x;
    int base = j * CHUNK;
    int nE = min(CHUNK, E - base);
    int NB1 = NBINS + 1;
    for (int i = t; i < MAXB; i += 256) { hD[i] = 0; hS[i] = 0; }
    __syncthreads();
    for (int i = t; i < nE; i += 256) {
        atomicAdd(&hD[dst[base + i] >> BIN_SHIFT], 1);
        atomicAdd(&hS[src[base + i] >> BIN_SHIFT], 1);
    }
    __syncthreads();
    if (t < MAXB) sd[t] = hD[t];
    __syncthreads();
    for (int off = 1; off < MAXB; off <<= 1) {
        int x = 0;
        if (t < MAXB && t >= off) x = sd[t - off];
        __syncthreads();
        if (t < MAXB) sd[t] += x;
        __syncthreads();
    }
    if (t < MAXB) cD[t] = sd[t] - hD[t];
    if (t < NBINS) bboD[(size_t)j * NB1 + t] = sd[t] - hD[t];
    if (t == NBINS) bboD[(size_t)j * NB1 + NBINS] = nE;
    __syncthreads();
    if (t < MAXB) sd[t] = hS[t];
    __syncthreads();
    for (int off = 1; off < MAXB; off <<= 1) {
        int x = 0;
        if (t < MAXB && t >= off) x = sd[t - off];
        __syncthreads();
        if (t < MAXB) sd[t] += x;
        __syncthreads();
    }
    if (t < MAXB) cS[t] = sd[t] - hS[t];
    if (t < NBINS) bboS[(size_t)j * NB1 + t] = sd[t] - hS[t];
    if (t == NBINS) bboS[(size_t)j * NB1 + NBINS] = nE;
    __syncthreads();
    for (int i = t; i < nE; i += 256) {
        int s = src[base + i], d = dst[base + i];
        int pD = atomicAdd(&cD[d >> BIN_SHIFT], 1);
        stD[(size_t)base + pD] = ((uint32_t)(d & (BIN_SIZE - 1)) << 17) | (uint32_t)s;
        int pS = atomicAdd(&cS[s >> BIN_SHIFT], 1);
        stS[(size_t)base + pS] = (unsigned short)(s & (BIN_SIZE - 1));
    }
}

// ---------------- merged degree kernel: z==0 dst (+hsave persist), z==1 src ----------------
__global__ __launch_bounds__(256) void k_deg(const uint32_t* __restrict__ stD, const int* __restrict__ bboD,
                                             const unsigned short* __restrict__ stS, const int* __restrict__ bboS,
                                             int* __restrict__ deg_in, int* __restrict__ deg_out,
                                             int* __restrict__ hsave, int nchunk, int NBINS) {
    __shared__ int hist[BIN_SIZE];
    int b = blockIdx.x, g = blockIdx.y, t = threadIdx.x;
    int wv = t >> 6, lane = t & 63;
    int NB1 = NBINS + 1;
    for (int i = t; i < BIN_SIZE; i += 256) hist[i] = 0;
    __syncthreads();
    int base = b << BIN_SHIFT;
    if (blockIdx.z == 0) {
        for (int j = g * 4 + wv; j < nchunk; j += GSPLIT * 4) {
            int s = bboD[(size_t)j * NB1 + b], e = bboD[(size_t)j * NB1 + b + 1];
            const uint32_t* seg = stD + (size_t)j * CHUNK;
            for (int i = s + lane; i < e; i += 64)
                atomicAdd(&hist[seg[i] >> 17], 1);
        }
        __syncthreads();
        int* hp = hsave + ((size_t)(b * GSPLIT + g) << BIN_SHIFT);
        for (int i = t; i < BIN_SIZE; i += 256) {
            int v = hist[i];
            hp[i] = v;
            if (v) atomicAdd(&deg_in[base + i], v);
        }
    } else {
        for (int j = g * 4 + wv; j < nchunk; j += GSPLIT * 4) {
            int s = bboS[(size_t)j * NB1 + b], e = bboS[(size_t)j * NB1 + b + 1];
            const unsigned short* seg = stS + (size_t)j * CHUNK;
            for (int i = s + lane; i < e; i += 64)
                atomicAdd(&hist[seg[i]], 1);
        }
        __syncthreads();
        for (int i = t; i < BIN_SIZE; i += 256) {
            int v = hist[i];
            if (v) atomicAdd(&deg_out[base + i], v);
        }
    }
}

// col scatter: reuses the histogram saved by k_deg (same chunk partition per (b,g)),
// so only ONE pass over stD remains here.
__global__ __launch_bounds__(256) void k_col(const uint32_t* __restrict__ stD, const int* __restrict__ bboD,
                                             const int* __restrict__ hsave, int* __restrict__ cursor,
                                             int* __restrict__ col, int N, int nchunk, int NBINS) {
    __shared__ int hist[BIN_SIZE];
    int b = blockIdx.x, g = blockIdx.y, t = threadIdx.x;
    int wv = t >> 6, lane = t & 63;
    int NB1 = NBINS + 1;
    int base = b << BIN_SHIFT;
    const int* hp = hsave + ((size_t)(b * GSPLIT + g) << BIN_SHIFT);
    for (int i = t; i < BIN_SIZE; i += 256) {
        int v = hp[i];
        hist[i] = v ? atomicAdd(&cursor[base + i], v) : 0;
    }
    __syncthreads();
    for (int j = g * 4 + wv; j < nchunk; j += GSPLIT * 4) {
        int s = bboD[(size_t)j * NB1 + b], e = bboD[(size_t)j * NB1 + b + 1];
        const uint32_t* seg = stD + (size_t)j * CHUNK;
        for (int i = s + lane; i < e; i += 64) {
            uint32_t v = seg[i];
            int pos = atomicAdd(&hist[v >> 17], 1);
            col[pos] = (int)(v & 0x1FFFFu);
        }
    }
}

__global__ __launch_bounds__(256) void k_scan1(const int* __restrict__ deg, int* __restrict__ out,
                                               int* __restrict__ bsum, float* __restrict__ rs_in, int n) {
    __shared__ int sd[256];
    int t = threadIdx.x, b = blockIdx.x;
    int base = b * 1024 + t * 4;
    int v0 = 0, v1 = 0, v2 = 0, v3 = 0;
    if (base + 0 < n) v0 = deg[base + 0];
    if (base + 1 < n) v1 = deg[base + 1];
    if (base + 2 < n) v2 = deg[base + 2];
    if (base + 3 < n) v3 = deg[base + 3];
    if (base + 0 < n) rs_in[base + 0] = rsqrtf((float)max(v0, 1));
    if (base + 1 < n) rs_in[base + 1] = rsqrtf((float)max(v1, 1));
    if (base + 2 < n) rs_in[base + 2] = rsqrtf((float)max(v2, 1));
    if (base + 3 < n) rs_in[base + 3] = rsqrtf((float)max(v3, 1));
    int ts = v0 + v1 + v2 + v3;
    sd[t] = ts;
    __syncthreads();
    for (int off = 1; off < 256; off <<= 1) {
        int x = 0;
        if (t >= off) x = sd[t - off];
        __syncthreads();
        sd[t] += x;
        __syncthreads();
    }
    int excl = sd[t] - ts;
    if (base + 0 < n) out[base + 0] = excl;
    if (base + 1 < n) out[base + 1] = excl + v0;
    if (base + 2 < n) out[base + 2] = excl + v0 + v1;
    if (base + 3 < n) out[base + 3] = excl + v0 + v1 + v2;
    if (t == 255) bsum[b] = sd[255];
}

__global__ __launch_bounds__(1024) void k_scan2(int* __restrict__ bsum, int nb) {
    __shared__ int sd[1024];
    int t = threadIdx.x;
    int v = (t < nb) ? bsum[t] : 0;
    sd[t] = v;
    __syncthreads();
    for (int off = 1; off < 1024; off <<= 1) {
        int x = 0;
        if (t >= off) x = sd[t - off];
        __syncthreads();
        sd[t] += x;
        __syncthreads();
    }
    if (t < nb) bsum[t] = sd[t] - v;   // exclusive
}

__global__ __launch_bounds__(256) void k_scan3(int* __restrict__ row_ptr, const int* __restrict__ bsum,
                                               int* __restrict__ cursor, const int* __restrict__ deg_out,
                                               float* __restrict__ rs_out, int n, int E) {
    int i = blockIdx.x * 256 + threadIdx.x;
    if (i < n) {
        int v = row_ptr[i] + bsum[i >> 10];
        row_ptr[i] = v;
        cursor[i] = v;
        rs_out[i] = rsqrtf((float)max(deg_out[i], 1));
    }
    if (i == 0) row_ptr[n] = E;
}

// ---------------- GEMM1 (bf16 MFMA): h1f = fp8((h @ W1) * rs_out[row]), permuted columns ----------------
__global__ __launch_bounds__(256) void k_gemm1(const float* __restrict__ A, const short* __restrict__ Wg,
                                               const float* __restrict__ rs_out, uint32_t* __restrict__ h1f, int M) {
    __shared__ short As[64 * 264];            // [row][k], k-pitch 264 (33 KB)
    int t = threadIdx.x;
    int lane = t & 63, wv = t >> 6;
    int block_row = blockIdx.x * 64;
#pragma unroll
    for (int i = 0; i < 16; ++i) {
        int u = t + i * 256;                  // 4096 float4 units
        int row = u >> 6, kq = (u & 63) * 4;
        int gr = block_row + row;
        float4 v = {0.f, 0.f, 0.f, 0.f};
        if (gr < M) v = *(const float4*)(A + (size_t)gr * IN_DIM + kq);
        short4 sv = {f2bf(v.x), f2bf(v.y), f2bf(v.z), f2bf(v.w)};
        *(short4*)&As[row * 264 + kq] = sv;
    }
    __syncthreads();
    f32x4 acc[8] = {};
    int arow = (wv * 16 + (lane & 15)) * 264 + (lane >> 4) * 8;
#pragma unroll
    for (int ks = 0; ks < 8; ++ks) {
        short8 a = *(short8*)&As[arow + ks * 32];
#pragma unroll
        for (int nt = 0; nt < 8; ++nt) {
            short8 b = *(const short8*)&Wg[(((nt * 8 + ks) * 64) + lane) * 8];
            acc[nt] = __builtin_amdgcn_mfma_f32_16x16x32_bf16(a, b, acc[nt], 0, 0, 0);
        }
    }
    int quad = lane >> 4, cl = lane & 15;
#pragma unroll
    for (int r = 0; r < 4; ++r) {
        int gr = block_row + wv * 16 + quad * 4 + r;
        if (gr >= M) continue;
        float sc = rs_out[gr];
        int d0 = __builtin_amdgcn_cvt_pk_fp8_f32(acc[0][r] * sc, acc[1][r] * sc, 0, false);
        d0 = __builtin_amdgcn_cvt_pk_fp8_f32(acc[2][r] * sc, acc[3][r] * sc, d0, true);
        int d1 = __builtin_amdgcn_cvt_pk_fp8_f32(acc[4][r] * sc, acc[5][r] * sc, 0, false);
        d1 = __builtin_amdgcn_cvt_pk_fp8_f32(acc[6][r] * sc, acc[7][r] * sc, d1, true);
        uint2 dd = make_uint2((uint32_t)d0, (uint32_t)d1);
        *(uint2*)((char*)h1f + (size_t)gr * 128 + cl * 8) = dd;
    }
}

// ---------------- Fused SpMM1 + ReLU + GEMM2 ----------------
// Block = 256 threads = 4 waves = 4 nodes (ONE node per wave, same scheduling as the proven spmm1).
// Gather: 16 lanes/edge x uint2 (8B), 4 edge-groups -> 2-level xor reduce (8 accs).
// x1 rows parked in LDS rows 0..3 (bf16, XOR-swizzled); rows 4..15 are garbage but C rows are
// row-independent, so only nodes < vr are stored. 12 MFMAs -> h2f fp8, rows PADDED to 64 B.
__global__ __launch_bounds__(256) void k_spmm1f(const uint2* __restrict__ h1f2, const int* __restrict__ rp,
                                                const int* __restrict__ col, const float* __restrict__ rs_in,
                                                const float* __restrict__ rs_out, const float* __restrict__ b1p,
                                                const short* __restrict__ Wg2,
                                                uint32_t* __restrict__ h2f, int N) {
    __shared__ uint32_t x1s[16 * 64];   // 16 rows x 256 B (only rows 0..3 written), 16B-granule XOR swizzle
    __shared__ uint32_t hs[4 * 16];     // 4 x 64 B fp8 staging (bytes 40..63 zeroed)
    int t = threadIdx.x;
    int wv = t >> 6, lane = t & 63;
    int grp = lane >> 4, ql = lane & 15;
    int w_base = blockIdx.x * 4;
    int w = w_base + wv;

    int ntl = (wv < 3) ? wv : 0;
    short8 wf0 = *(const short8*)&Wg2[((ntl * 4 + 0) * 64 + lane) * 8];
    short8 wf1 = *(const short8*)&Wg2[((ntl * 4 + 1) * 64 + lane) * 8];
    short8 wf2 = *(const short8*)&Wg2[((ntl * 4 + 2) * 64 + lane) * 8];
    short8 wf3 = *(const short8*)&Wg2[((ntl * 4 + 3) * 64 + lane) * 8];
    float4 blo = *(const float4*)&b1p[ql * 8];
    float4 bhi = *(const float4*)&b1p[ql * 8 + 4];
    if (t < 24) hs[(t / 6) * 16 + 10 + (t % 6)] = 0;   // zero pad dwords 10..15 of each 64B row

    if (w < N) {
        int s = rp[w], e = rp[w + 1];
        float acc[8] = {};
        int i = s;
        while (i < e) {
            int cnt = min(64, e - i);
            int cl = (lane < cnt) ? lane : cnt - 1;
            int cidx = col[i + cl];
            for (int it = 0; it < cnt; it += 8) {
                int eA = it + grp, eB = it + 4 + grp;
                int cA = __shfl(cidx, eA, 64);
                int cB = __shfl(cidx, eB, 64);
                float mA = (eA < cnt) ? 1.f : 0.f;
                float mB = (eB < cnt) ? 1.f : 0.f;
                uint2 uA = h1f2[(size_t)cA * 16 + ql];
                uint2 uB = h1f2[(size_t)cB * 16 + ql];
                {
                    f32x2 p0 = __builtin_amdgcn_cvt_pk_f32_fp8(uA.x, false);
                    f32x2 p1 = __builtin_amdgcn_cvt_pk_f32_fp8(uA.x, true);
                    f32x2 p2 = __builtin_amdgcn_cvt_pk_f32_fp8(uA.y, false);
                    f32x2 p3 = __builtin_amdgcn_cvt_pk_f32_fp8(uA.y, true);
                    acc[0] = fmaf(p0.x, mA, acc[0]); acc[1] = fmaf(p0.y, mA, acc[1]);
                    acc[2] = fmaf(p1.x, mA, acc[2]); acc[3] = fmaf(p1.y, mA, acc[3]);
                    acc[4] = fmaf(p2.x, mA, acc[4]); acc[5] = fmaf(p2.y, mA, acc[5]);
                    acc[6] = fmaf(p3.x, mA, acc[6]); acc[7] = fmaf(p3.y, mA, acc[7]);
                }
                {
                    f32x2 p0 = __builtin_amdgcn_cvt_pk_f32_fp8(uB.x, false);
                    f32x2 p1 = __builtin_amdgcn_cvt_pk_f32_fp8(uB.x, true);
                    f32x2 p2 = __builtin_amdgcn_cvt_pk_f32_fp8(uB.y, false);
                    f32x2 p3 = __builtin_amdgcn_cvt_pk_f32_fp8(uB.y, true);
                    acc[0] = fmaf(p0.x, mB, acc[0]); acc[1] = fmaf(p0.y, mB, acc[1]);
                    acc[2] = fmaf(p1.x, mB, acc[2]); acc[3] = fmaf(p1.y, mB, acc[3]);
                    acc[4] = fmaf(p2.x, mB, acc[4]); acc[5] = fmaf(p2.y, mB, acc[5]);
                    acc[6] = fmaf(p3.x, mB, acc[6]); acc[7] = fmaf(p3.y, mB, acc[7]);
                }
            }
            i += cnt;
        }
        // fold the 4 edge-groups (lane bits 4,5)
#pragma unroll
        for (int j = 0; j < 8; ++j) {
            acc[j] += __shfl_xor(acc[j], 16, 64);
            acc[j] += __shfl_xor(acc[j], 32, 64);
        }
        if (lane < 16) {
            float sc = rs_in[w];
            float f0, f1;
            uint32_t o0, o1, o2, o3;
            f0 = fmaxf(fmaf(acc[0], sc, blo.x), 0.f); f1 = fmaxf(fmaf(acc[1], sc, blo.y), 0.f);
            o0 = (uint32_t)(unsigned short)f2bf(f0) | ((uint32_t)(unsigned short)f2bf(f1) << 16);
            f0 = fmaxf(fmaf(acc[2], sc, blo.z), 0.f); f1 = fmaxf(fmaf(acc[3], sc, blo.w), 0.f);
            o1 = (uint32_t)(unsigned short)f2bf(f0) | ((uint32_t)(unsigned short)f2bf(f1) << 16);
            f0 = fmaxf(fmaf(acc[4], sc, bhi.x), 0.f); f1 = fmaxf(fmaf(acc[5], sc, bhi.y), 0.f);
            o2 = (uint32_t)(unsigned short)f2bf(f0) | ((uint32_t)(unsigned short)f2bf(f1) << 16);
            f0 = fmaxf(fmaf(acc[6], sc, bhi.z), 0.f); f1 = fmaxf(fmaf(acc[7], sc, bhi.w), 0.f);
            o3 = (uint32_t)(unsigned short)f2bf(f0) | ((uint32_t)(unsigned short)f2bf(f1) << 16);
            int woff = (wv * 256 + ql * 16) ^ ((wv & 7) << 4);
            *(uint4*)((char*)x1s + woff) = make_uint4(o0, o1, o2, o3);
        }
    }
    __syncthreads();
    int vr = min(4, N - w_base);
    if (wv < 3) {
        int row = lane & 15, kc = lane >> 4;
        int rbase = row * 256 + kc * 16;
        int swz = (row & 7) << 4;
        f32x4 c = {};
        c = __builtin_amdgcn_mfma_f32_16x16x32_bf16(*(short8*)((char*)x1s + ((rbase + 0) ^ swz)),   wf0, c, 0, 0, 0);
        c = __builtin_amdgcn_mfma_f32_16x16x32_bf16(*(short8*)((char*)x1s + ((rbase + 64) ^ swz)),  wf1, c, 0, 0, 0);
        c = __builtin_amdgcn_mfma_f32_16x16x32_bf16(*(short8*)((char*)x1s + ((rbase + 128) ^ swz)), wf2, c, 0, 0, 0);
        c = __builtin_amdgcn_mfma_f32_16x16x32_bf16(*(short8*)((char*)x1s + ((rbase + 192) ^ swz)), wf3, c, 0, 0, 0);
        int cc = wv * 16 + row;     // output column 0..47 (only <40 valid)
        if (cc < OUT_DIM && kc == 0) {    // C rows 0..3 live in kc==0 lanes
#pragma unroll
            for (int r = 0; r < 4; ++r) {
                if (r < vr) {
                    float v = c[r] * rs_out[w_base + r];
                    int pk = __builtin_amdgcn_cvt_pk_fp8_f32(v, v, 0, false);
                    ((unsigned char*)hs)[r * 64 + cc] = (unsigned char)(pk & 0xff);
                }
            }
        }
    }
    __syncthreads();
    uint32_t* dp = h2f + (size_t)w_base * 16;
    for (int idx = t; idx < vr * 16; idx += 256) dp[idx] = hs[idx];
}

// ---------------- SpMM2 (fp8, 64B-padded rows) + bias + log_softmax ----------------
// 8 lanes/edge x uint2 (exactly one 64 B line per edge), 8 edge-groups, 3-level xor fold.
__global__ __launch_bounds__(256) void k_spmm2(const uint2* __restrict__ h2f2, const int* __restrict__ rp,
                                               const int* __restrict__ col, const float* __restrict__ rs_in,
                                               const float* __restrict__ b2, float* __restrict__ out, int n) {
    int w = (blockIdx.x * 256 + threadIdx.x) >> 6;
    int lane = threadIdx.x & 63;
    if (w >= n) return;
    int grp = lane >> 3, fl = lane & 7;       // fl: feature-byte group (fl<5 real, 5..7 pad=0)
    int s = rp[w], e = rp[w + 1];
    float acc[8] = {};
    int i = s;
    while (i < e) {
        int cnt = min(64, e - i);
        int cl = (lane < cnt) ? lane : cnt - 1;
        int cidx = col[i + cl];
        for (int it = 0; it < cnt; it += 16) {
            int eA = it + grp, eB = it + 8 + grp;
            int cA = __shfl(cidx, eA, 64);
            int cB = __shfl(cidx, eB, 64);
            float mA = (eA < cnt) ? 1.f : 0.f;
            float mB = (eB < cnt) ? 1.f : 0.f;
            uint2 uA = h2f2[(size_t)cA * 8 + fl];
            uint2 uB = h2f2[(size_t)cB * 8 + fl];
            {
                f32x2 p0 = __builtin_amdgcn_cvt_pk_f32_fp8(uA.x, false);
                f32x2 p1 = __builtin_amdgcn_cvt_pk_f32_fp8(uA.x, true);
                f32x2 p2 = __builtin_amdgcn_cvt_pk_f32_fp8(uA.y, false);
                f32x2 p3 = __builtin_amdgcn_cvt_pk_f32_fp8(uA.y, true);
                acc[0] = fmaf(p0.x, mA, acc[0]); acc[1] = fmaf(p0.y, mA, acc[1]);
                acc[2] = fmaf(p1.x, mA, acc[2]); acc[3] = fmaf(p1.y, mA, acc[3]);
                acc[4] = fmaf(p2.x, mA, acc[4]); acc[5] = fmaf(p2.y, mA, acc[5]);
                acc[6] = fmaf(p3.x, mA, acc[6]); acc[7] = fmaf(p3.y, mA, acc[7]);
            }
            {
                f32x2 p0 = __builtin_amdgcn_cvt_pk_f32_fp8(uB.x, false);
                f32x2 p1 = __builtin_amdgcn_cvt_pk_f32_fp8(uB.x, true);
                f32x2 p2 = __builtin_amdgcn_cvt_pk_f32_fp8(uB.y, false);
                f32x2 p3 = __builtin_amdgcn_cvt_pk_f32_fp8(uB.y, true);
                acc[0] = fmaf(p0.x, mB, acc[0]); acc[1] = fmaf(p0.y, mB, acc[1]);
                acc[2] = fmaf(p1.x, mB, acc[2]); acc[3] = fmaf(p1.y, mB, acc[3]);
                acc[4] = fmaf(p2.x, mB, acc[4]); acc[5] = fmaf(p2.y, mB, acc[5]);
                acc[6] = fmaf(p3.x, mB, acc[6]); acc[7] = fmaf(p3.y, mB, acc[7]);
            }
        }
        i += cnt;
    }
    // fold 8 edge-groups (lane bits 3,4,5)
#pragma unroll
    for (int j = 0; j < 8; ++j) {
        acc[j] += __shfl_xor(acc[j], 8, 64);
        acc[j] += __shfl_xor(acc[j], 16, 64);
        acc[j] += __shfl_xor(acc[j], 32, 64);
    }
    bool act = lane < 5;
    float sc = rs_in[w];
    int bb = (fl < 5) ? fl * 8 : 0;           // guard b2 OOB for pad lanes
    float val[8];
#pragma unroll
    for (int j = 0; j < 8; ++j)
        val[j] = fmaf(acc[j], sc, b2[bb + j]);
    float pm = -INFINITY;
    if (act) {
        pm = val[0];
#pragma unroll
        for (int j = 1; j < 8; ++j) pm = fmaxf(pm, val[j]);
    }
    pm = fmaxf(pm, __shfl_xor(pm, 4, 8));
    pm = fmaxf(pm, __shfl_xor(pm, 2, 8));
    pm = fmaxf(pm, __shfl_xor(pm, 1, 8));
    float ex = 0.f;
    if (act) {
#pragma unroll
        for (int j = 0; j < 8; ++j) ex += expf(val[j] - pm);
    }
    ex += __shfl_xor(ex, 4, 8);
    ex += __shfl_xor(ex, 2, 8);
    ex += __shfl_xor(ex, 1, 8);
    if (act) {
        float l = pm + logf(ex);
        float4 o0 = {val[0] - l, val[1] - l, val[2] - l, val[3] - l};
        float4 o1 = {val[4] - l, val[5] - l, val[6] - l, val[7] - l};
        float* op = out + (size_t)w * OUT_DIM + lane * 8;
        *(float4*)op = o0;
        *(float4*)(op + 4) = o1;
    }
}

// ---------------- launch ----------------

extern "C" void kernel_launch(void* const* d_in, const int* in_sizes, int n_in,
                              void* d_out, int out_size, void* d_ws, size_t ws_size,
                              hipStream_t stream) {
    const int N = in_sizes[0] / IN_DIM;
    const int E = in_sizes[5];
    const float* h  = (const float*)d_in[0];
    const float* W1 = (const float*)d_in[1];
    const float* b1 = (const float*)d_in[2];
    const float* W2 = (const float*)d_in[3];
    const float* b2 = (const float*)d_in[4];
    const int* src  = (const int*)d_in[5];
    const int* dst  = (const int*)d_in[6];
    float* out = (float*)d_out;

    const int NBINS  = (N + BIN_SIZE - 1) >> BIN_SHIFT;   // 98
    const int NCHUNK = (E + CHUNK - 1) / CHUNK;           // 391

    char* w = (char*)d_ws;
    size_t off = 0;
    auto alloc = [&](size_t bytes) -> void* {
        void* p = w + off;
        off += (bytes + 255) & ~(size_t)255;
        return p;
    };
    int* deg_in   = (int*)alloc((size_t)N * 4);
    int* deg_out  = (int*)alloc((size_t)N * 4);
    int* row_ptr  = (int*)alloc((size_t)(N + 1) * 4);
    int* cursor   = (int*)alloc((size_t)N * 4);
    int* bsum     = (int*)alloc(1024 * 4);
    float* rs_out = (float*)alloc((size_t)N * 4);
    float* rs_in  = (float*)alloc((size_t)N * 4);
    int* col      = (int*)alloc((size_t)E * 4);
    int* bboD     = (int*)alloc((size_t)NCHUNK * (NBINS + 1) * 4);
    int* bboS     = (int*)alloc((size_t)NCHUNK * (NBINS + 1) * 4);
    short* Wg     = (short*)alloc((size_t)8 * 8 * 64 * 8 * 2);    // 64 KB
    short* Wg2    = (short*)alloc((size_t)3 * 4 * 64 * 8 * 2);    // 12 KB
    float* b1p    = (float*)alloc((size_t)HID * 4);
    int* hsave    = (int*)alloc((size_t)NBINS * GSPLIT * BIN_SIZE * 4);   // 3.2 MB
    // staging regions; dead before their aliases are written (stream-ordered):
    //   stD read last by k_col, then k_gemm1 writes h1f over it.
    //   stS read last by k_deg (src pass), then k_spmm1f writes h2f over it.
    size_t stD_bytes = (size_t)E * 4;  if ((size_t)N * HID > stD_bytes) stD_bytes = (size_t)N * HID;
    size_t stS_bytes = (size_t)E * 2;  if ((size_t)N * 64 > stS_bytes) stS_bytes = (size_t)N * 64;
    uint32_t* stD = (uint32_t*)alloc(stD_bytes);
    unsigned short* stS = (unsigned short*)alloc(stS_bytes);
    uint32_t* h1f = (uint32_t*)stD;                       // fp8 [N][128], 12.8 MB
    uint32_t* h2f = (uint32_t*)stS;                       // fp8 [N][64] (40 real + 24 pad), 6.4 MB

    int gN = (N + 255) / 256;
    int NB = (N + 1023) / 1024;
    int Z = (N + 3) / 4;
    int setup_units = 8192 + 3 * 4 * 64 * 8 + HID + 2 * Z;
    int gsetup = (setup_units + 255) / 256;

    k_setup<<<gsetup, 256, 0, stream>>>(W1, W2, b1, Wg, Wg2, b1p, deg_in, deg_out, Z);
    k_binscatter<<<NCHUNK, 256, 0, stream>>>(src, dst, stD, stS, bboD, bboS, E, NBINS);
    k_deg<<<dim3(NBINS, GSPLIT, 2), 256, 0, stream>>>(stD, bboD, stS, bboS, deg_in, deg_out, hsave, NCHUNK, NBINS);
    k_scan1<<<NB, 256, 0, stream>>>(deg_in, row_ptr, bsum, rs_in, N);
    k_scan2<<<1, 1024, 0, stream>>>(bsum, NB);
    k_scan3<<<gN, 256, 0, stream>>>(row_ptr, bsum, cursor, deg_out, rs_out, N, E);
    k_col<<<dim3(NBINS, GSPLIT), 256, 0, stream>>>(stD, bboD, hsave, cursor, col, N, NCHUNK, NBINS);
    k_gemm1<<<(N + 63) / 64, 256, 0, stream>>>(h, Wg, rs_out, h1f, N);
    k_spmm1f<<<(N + 3) / 4, 256, 0, stream>>>((const uint2*)h1f, row_ptr, col, rs_in, rs_out, b1p, Wg2, h2f, N);
    k_spmm2<<<(N + 3) / 4, 256, 0, stream>>>((const uint2*)h2f, row_ptr, col, rs_in, b2, out, N);
}

// Round 3
// 463.127 us; speedup vs baseline: 1.1346x; 1.0092x over previous
//
#include <hip/hip_runtime.h>
#include <hip/hip_bf16.h>
#include <cstddef>
#include <cstdint>

#define IN_DIM 256
#define HID 128
#define OUT_DIM 40

#define CHUNK 8192      // edges per binscatter block (private staging region)
#define BIN_SHIFT 10    // 1024 nodes per bin
#define BIN_SIZE 1024
#define MAXB 128        // >= NBINS+1
#define GSPLIT 8        // blocks per bin for deg/col kernels

typedef __attribute__((ext_vector_type(8))) short short8;
typedef __attribute__((ext_vector_type(4))) float f32x4;
typedef __attribute__((ext_vector_type(2))) float f32x2;

__device__ inline short f2bf(float f) {
    __hip_bfloat16 b = __float2bfloat16(f);   // RNE
    return __builtin_bit_cast(short, b);
}
__device__ inline float bf2f(unsigned short u) {
    unsigned int v = (unsigned int)u << 16;
    return __builtin_bit_cast(float, v);
}
// feature permutation for h1/x1 storage: slot p holds feature (p>>3) + 16*(p&7).
__device__ inline int permf(int p) { return (p >> 3) + 16 * (p & 7); }

// ---------------- setup: W1 repack + W2 repack + b1 permute + deg zeroing (one launch) ----------------
__global__ __launch_bounds__(256) void k_setup(const float* __restrict__ W1, const float* __restrict__ W2,
                                               const float* __restrict__ b1, short* __restrict__ Wg,
                                               short* __restrict__ Wg2, float* __restrict__ b1p,
                                               int* __restrict__ deg_in, int* __restrict__ deg_out, int Z) {
    int flat = blockIdx.x * 256 + threadIdx.x;
    if (flat < 8192) {                        // W1: fp32 [256][128] -> bf16 fragments [nt][ks][lane][8]
        int k = flat >> 5;                    // 0..255
        int n0 = (flat & 31) * 4;
        float4 v = *(const float4*)(W1 + (size_t)k * HID + n0);
        int ks = k >> 5, quad = (k >> 3) & 3, j = k & 7;
        float vv[4] = {v.x, v.y, v.z, v.w};
#pragma unroll
        for (int e = 0; e < 4; ++e) {
            int n = n0 + e;
            int nt = n >> 4;
            int ln = (n & 15) | (quad << 4);
            Wg[(((nt * 8 + ks) * 64) + ln) * 8 + j] = f2bf(vv[e]);
        }
        return;
    }
    flat -= 8192;
    if (flat < 3 * 4 * 64 * 8) {              // W2: fp32 [128][40] -> bf16 B-fragments (pad cols 40->48)
        int f = flat >> 9;                    // 0..11
        int ln = (flat >> 3) & 63;
        int j = flat & 7;
        int nt = f >> 2, ks = f & 3;
        int q = ks * 32 + (ln >> 4) * 8 + j;  // x1 slot (permuted feature index)
        int c = nt * 16 + (ln & 15);          // output col
        float v = (c < OUT_DIM) ? W2[(size_t)permf(q) * OUT_DIM + c] : 0.f;
        Wg2[flat] = f2bf(v);
        return;
    }
    flat -= 3 * 4 * 64 * 8;
    if (flat < HID) { b1p[flat] = b1[permf(flat)]; return; }
    flat -= HID;
    if (flat < Z) { *(int4*)(deg_in + flat * 4) = make_int4(0, 0, 0, 0); return; }
    flat -= Z;
    if (flat < Z) { *(int4*)(deg_out + flat * 4) = make_int4(0, 0, 0, 0); }
}

// ---------------- CSR build: chunk-private counting sort by dst/src bin ----------------
__global__ __launch_bounds__(256) void k_binscatter(const int* __restrict__ src, const int* __restrict__ dst,
                                                    uint32_t* __restrict__ stD, unsigned short* __restrict__ stS,
                                                    int* __restrict__ bboD, int* __restrict__ bboS,
                                                    int E, int NBINS) {
    __shared__ int hD[MAXB], hS[MAXB], cD[MAXB], cS[MAXB], sd[MAXB];
    int j = blockIdx.x, t = threadIdx.x;
    int base = j * CHUNK;
    int nE = min(CHUNK, E - base);
    int NB1 = NBINS + 1;
    for (int i = t; i < MAXB; i += 256) { hD[i] = 0; hS[i] = 0; }
    __syncthreads();
    for (int i = t; i < nE; i += 256) {
        atomicAdd(&hD[dst[base + i] >> BIN_SHIFT], 1);
        atomicAdd(&hS[src[base + i] >> BIN_SHIFT], 1);
    }
    __syncthreads();
    if (t < MAXB) sd[t] = hD[t];
    __syncthreads();
    for (int off = 1; off < MAXB; off <<= 1) {
        int x = 0;
        if (t < MAXB && t >= off) x = sd[t - off];
        __syncthreads();
        if (t < MAXB) sd[t] += x;
        __syncthreads();
    }
    if (t < MAXB) cD[t] = sd[t] - hD[t];
    if (t < NBINS) bboD[(size_t)j * NB1 + t] = sd[t] - hD[t];
    if (t == NBINS) bboD[(size_t)j * NB1 + NBINS] = nE;
    __syncthreads();
    if (t < MAXB) sd[t] = hS[t];
    __syncthreads();
    for (int off = 1; off < MAXB; off <<= 1) {
        int x = 0;
        if (t < MAXB && t >= off) x = sd[t - off];
        __syncthreads();
        if (t < MAXB) sd[t] += x;
        __syncthreads();
    }
    if (t < MAXB) cS[t] = sd[t] - hS[t];
    if (t < NBINS) bboS[(size_t)j * NB1 + t] = sd[t] - hS[t];
    if (t == NBINS) bboS[(size_t)j * NB1 + NBINS] = nE;
    __syncthreads();
    for (int i = t; i < nE; i += 256) {
        int s = src[base + i], d = dst[base + i];
        int pD = atomicAdd(&cD[d >> BIN_SHIFT], 1);
        stD[(size_t)base + pD] = ((uint32_t)(d & (BIN_SIZE - 1)) << 17) | (uint32_t)s;
        int pS = atomicAdd(&cS[s >> BIN_SHIFT], 1);
        stS[(size_t)base + pS] = (unsigned short)(s & (BIN_SIZE - 1));
    }
}

// ---------------- merged degree kernel: z==0 dst (+hsave persist), z==1 src ----------------
__global__ __launch_bounds__(256) void k_deg(const uint32_t* __restrict__ stD, const int* __restrict__ bboD,
                                             const unsigned short* __restrict__ stS, const int* __restrict__ bboS,
                                             int* __restrict__ deg_in, int* __restrict__ deg_out,
                                             int* __restrict__ hsave, int nchunk, int NBINS) {
    __shared__ int hist[BIN_SIZE];
    int b = blockIdx.x, g = blockIdx.y, t = threadIdx.x;
    int wv = t >> 6, lane = t & 63;
    int NB1 = NBINS + 1;
    for (int i = t; i < BIN_SIZE; i += 256) hist[i] = 0;
    __syncthreads();
    int base = b << BIN_SHIFT;
    if (blockIdx.z == 0) {
        for (int j = g * 4 + wv; j < nchunk; j += GSPLIT * 4) {
            int s = bboD[(size_t)j * NB1 + b], e = bboD[(size_t)j * NB1 + b + 1];
            const uint32_t* seg = stD + (size_t)j * CHUNK;
            for (int i = s + lane; i < e; i += 64)
                atomicAdd(&hist[seg[i] >> 17], 1);
        }
        __syncthreads();
        int* hp = hsave + ((size_t)(b * GSPLIT + g) << BIN_SHIFT);
        for (int i = t; i < BIN_SIZE; i += 256) {
            int v = hist[i];
            hp[i] = v;
            if (v) atomicAdd(&deg_in[base + i], v);
        }
    } else {
        for (int j = g * 4 + wv; j < nchunk; j += GSPLIT * 4) {
            int s = bboS[(size_t)j * NB1 + b], e = bboS[(size_t)j * NB1 + b + 1];
            const unsigned short* seg = stS + (size_t)j * CHUNK;
            for (int i = s + lane; i < e; i += 64)
                atomicAdd(&hist[seg[i]], 1);
        }
        __syncthreads();
        for (int i = t; i < BIN_SIZE; i += 256) {
            int v = hist[i];
            if (v) atomicAdd(&deg_out[base + i], v);
        }
    }
}

// col scatter: reuses the histogram saved by k_deg (same chunk partition per (b,g)),
// so only ONE pass over stD remains here.
__global__ __launch_bounds__(256) void k_col(const uint32_t* __restrict__ stD, const int* __restrict__ bboD,
                                             const int* __restrict__ hsave, int* __restrict__ cursor,
                                             int* __restrict__ col, int N, int nchunk, int NBINS) {
    __shared__ int hist[BIN_SIZE];
    int b = blockIdx.x, g = blockIdx.y, t = threadIdx.x;
    int wv = t >> 6, lane = t & 63;
    int NB1 = NBINS + 1;
    int base = b << BIN_SHIFT;
    const int* hp = hsave + ((size_t)(b * GSPLIT + g) << BIN_SHIFT);
    for (int i = t; i < BIN_SIZE; i += 256) {
        int v = hp[i];
        hist[i] = v ? atomicAdd(&cursor[base + i], v) : 0;
    }
    __syncthreads();
    for (int j = g * 4 + wv; j < nchunk; j += GSPLIT * 4) {
        int s = bboD[(size_t)j * NB1 + b], e = bboD[(size_t)j * NB1 + b + 1];
        const uint32_t* seg = stD + (size_t)j * CHUNK;
        for (int i = s + lane; i < e; i += 64) {
            uint32_t v = seg[i];
            int pos = atomicAdd(&hist[v >> 17], 1);
            col[pos] = (int)(v & 0x1FFFFu);
        }
    }
}

__global__ __launch_bounds__(256) void k_scan1(const int* __restrict__ deg, int* __restrict__ out,
                                               int* __restrict__ bsum, float* __restrict__ rs_in, int n) {
    __shared__ int sd[256];
    int t = threadIdx.x, b = blockIdx.x;
    int base = b * 1024 + t * 4;
    int v0 = 0, v1 = 0, v2 = 0, v3 = 0;
    if (base + 0 < n) v0 = deg[base + 0];
    if (base + 1 < n) v1 = deg[base + 1];
    if (base + 2 < n) v2 = deg[base + 2];
    if (base + 3 < n) v3 = deg[base + 3];
    if (base + 0 < n) rs_in[base + 0] = rsqrtf((float)max(v0, 1));
    if (base + 1 < n) rs_in[base + 1] = rsqrtf((float)max(v1, 1));
    if (base + 2 < n) rs_in[base + 2] = rsqrtf((float)max(v2, 1));
    if (base + 3 < n) rs_in[base + 3] = rsqrtf((float)max(v3, 1));
    int ts = v0 + v1 + v2 + v3;
    sd[t] = ts;
    __syncthreads();
    for (int off = 1; off < 256; off <<= 1) {
        int x = 0;
        if (t >= off) x = sd[t - off];
        __syncthreads();
        sd[t] += x;
        __syncthreads();
    }
    int excl = sd[t] - ts;
    if (base + 0 < n) out[base + 0] = excl;
    if (base + 1 < n) out[base + 1] = excl + v0;
    if (base + 2 < n) out[base + 2] = excl + v0 + v1;
    if (base + 3 < n) out[base + 3] = excl + v0 + v1 + v2;
    if (t == 255) bsum[b] = sd[255];
}

__global__ __launch_bounds__(1024) void k_scan2(int* __restrict__ bsum, int nb) {
    __shared__ int sd[1024];
    int t = threadIdx.x;
    int v = (t < nb) ? bsum[t] : 0;
    sd[t] = v;
    __syncthreads();
    for (int off = 1; off < 1024; off <<= 1) {
        int x = 0;
        if (t >= off) x = sd[t - off];
        __syncthreads();
        sd[t] += x;
        __syncthreads();
    }
    if (t < nb) bsum[t] = sd[t] - v;   // exclusive
}

__global__ __launch_bounds__(256) void k_scan3(int* __restrict__ row_ptr, const int* __restrict__ bsum,
                                               int* __restrict__ cursor, const int* __restrict__ deg_out,
                                               float* __restrict__ rs_out, int n, int E) {
    int i = blockIdx.x * 256 + threadIdx.x;
    if (i < n) {
        int v = row_ptr[i] + bsum[i >> 10];
        row_ptr[i] = v;
        cursor[i] = v;
        rs_out[i] = rsqrtf((float)max(deg_out[i], 1));
    }
    if (i == 0) row_ptr[n] = E;
}

// ---------------- GEMM1 (bf16 MFMA): h1f = fp8((h @ W1) * rs_out[row]), permuted columns ----------------
__global__ __launch_bounds__(256) void k_gemm1(const float* __restrict__ A, const short* __restrict__ Wg,
                                               const float* __restrict__ rs_out, uint32_t* __restrict__ h1f, int M) {
    __shared__ short As[64 * 264];            // [row][k], k-pitch 264 (33 KB)
    int t = threadIdx.x;
    int lane = t & 63, wv = t >> 6;
    int block_row = blockIdx.x * 64;
#pragma unroll
    for (int i = 0; i < 16; ++i) {
        int u = t + i * 256;                  // 4096 float4 units
        int row = u >> 6, kq = (u & 63) * 4;
        int gr = block_row + row;
        float4 v = {0.f, 0.f, 0.f, 0.f};
        if (gr < M) v = *(const float4*)(A + (size_t)gr * IN_DIM + kq);
        short4 sv = {f2bf(v.x), f2bf(v.y), f2bf(v.z), f2bf(v.w)};
        *(short4*)&As[row * 264 + kq] = sv;
    }
    __syncthreads();
    f32x4 acc[8] = {};
    int arow = (wv * 16 + (lane & 15)) * 264 + (lane >> 4) * 8;
#pragma unroll
    for (int ks = 0; ks < 8; ++ks) {
        short8 a = *(short8*)&As[arow + ks * 32];
#pragma unroll
        for (int nt = 0; nt < 8; ++nt) {
            short8 b = *(const short8*)&Wg[(((nt * 8 + ks) * 64) + lane) * 8];
            acc[nt] = __builtin_amdgcn_mfma_f32_16x16x32_bf16(a, b, acc[nt], 0, 0, 0);
        }
    }
    int quad = lane >> 4, cl = lane & 15;
#pragma unroll
    for (int r = 0; r < 4; ++r) {
        int gr = block_row + wv * 16 + quad * 4 + r;
        if (gr >= M) continue;
        float sc = rs_out[gr];
        int d0 = __builtin_amdgcn_cvt_pk_fp8_f32(acc[0][r] * sc, acc[1][r] * sc, 0, false);
        d0 = __builtin_amdgcn_cvt_pk_fp8_f32(acc[2][r] * sc, acc[3][r] * sc, d0, true);
        int d1 = __builtin_amdgcn_cvt_pk_fp8_f32(acc[4][r] * sc, acc[5][r] * sc, 0, false);
        d1 = __builtin_amdgcn_cvt_pk_fp8_f32(acc[6][r] * sc, acc[7][r] * sc, d1, true);
        uint2 dd = make_uint2((uint32_t)d0, (uint32_t)d1);
        *(uint2*)((char*)h1f + (size_t)gr * 128 + cl * 8) = dd;
    }
}

// ---------------- Fused SpMM1 + ReLU + GEMM2 ----------------
// Block = 256 threads = 4 waves = 4 nodes (one node per wave).
// Gather: 16 lanes/edge x uint2; 16 edges per it-step = 4 independent loads in flight.
// Hot loop is mask-free (full steps) + one masked tail step. Accumulate in f32x2 (v_pk_add_f32).
// x1 rows parked in LDS (bf16, XOR-swizzled); 12 MFMAs -> h2f fp8, rows padded to 64 B.
__global__ __launch_bounds__(256) void k_spmm1f(const char* __restrict__ h1c, const int* __restrict__ rp,
                                                const int* __restrict__ col, const float* __restrict__ rs_in,
                                                const float* __restrict__ rs_out, const float* __restrict__ b1p,
                                                const short* __restrict__ Wg2,
                                                uint32_t* __restrict__ h2f, int N) {
    __shared__ uint32_t x1s[16 * 64];   // 16 rows x 256 B (only rows 0..3 written), 16B-granule XOR swizzle
    __shared__ uint32_t hs2[48];        // column-major fp8 staging: dword cc = bytes for nodes 0..3
    int t = threadIdx.x;
    int wv = t >> 6, lane = t & 63;
    int grp = lane >> 4, ql = lane & 15;
    int w_base = blockIdx.x * 4;
    int w = w_base + wv;

    float4 blo = *(const float4*)&b1p[ql * 8];
    float4 bhi = *(const float4*)&b1p[ql * 8 + 4];

    if (w < N) {
        int s = rp[w], e = rp[w + 1];
        f32x2 a0 = {0.f, 0.f}, a1 = {0.f, 0.f}, a2 = {0.f, 0.f}, a3 = {0.f, 0.f};
        int qoff = ql << 3;
        int i = s;
        while (i < e) {
            int cnt = min(64, e - i);
            int cl = (lane < cnt) ? lane : cnt - 1;
            int rof = col[i + cl] << 7;          // byte offset of 128B row
            int nfull = cnt & ~15;
            int it = 0;
            for (; it < nfull; it += 16) {       // mask-free full steps, 4 loads in flight
                int o0 = __shfl(rof, it + grp, 64) + qoff;
                int o1 = __shfl(rof, it + 4 + grp, 64) + qoff;
                int o2 = __shfl(rof, it + 8 + grp, 64) + qoff;
                int o3 = __shfl(rof, it + 12 + grp, 64) + qoff;
                uint2 u0 = *(const uint2*)(h1c + (uint32_t)o0);
                uint2 u1 = *(const uint2*)(h1c + (uint32_t)o1);
                uint2 u2 = *(const uint2*)(h1c + (uint32_t)o2);
                uint2 u3 = *(const uint2*)(h1c + (uint32_t)o3);
                a0 += __builtin_amdgcn_cvt_pk_f32_fp8(u0.x, false);
                a1 += __builtin_amdgcn_cvt_pk_f32_fp8(u0.x, true);
                a2 += __builtin_amdgcn_cvt_pk_f32_fp8(u0.y, false);
                a3 += __builtin_amdgcn_cvt_pk_f32_fp8(u0.y, true);
                a0 += __builtin_amdgcn_cvt_pk_f32_fp8(u1.x, false);
                a1 += __builtin_amdgcn_cvt_pk_f32_fp8(u1.x, true);
                a2 += __builtin_amdgcn_cvt_pk_f32_fp8(u1.y, false);
                a3 += __builtin_amdgcn_cvt_pk_f32_fp8(u1.y, true);
                a0 += __builtin_amdgcn_cvt_pk_f32_fp8(u2.x, false);
                a1 += __builtin_amdgcn_cvt_pk_f32_fp8(u2.x, true);
                a2 += __builtin_amdgcn_cvt_pk_f32_fp8(u2.y, false);
                a3 += __builtin_amdgcn_cvt_pk_f32_fp8(u2.y, true);
                a0 += __builtin_amdgcn_cvt_pk_f32_fp8(u3.x, false);
                a1 += __builtin_amdgcn_cvt_pk_f32_fp8(u3.x, true);
                a2 += __builtin_amdgcn_cvt_pk_f32_fp8(u3.y, false);
                a3 += __builtin_amdgcn_cvt_pk_f32_fp8(u3.y, true);
            }
            if (it < cnt) {                      // one masked tail step (<=15 edges)
                int e0 = it + grp;               // e0+12 <= 63 always
                int o0 = __shfl(rof, e0, 64) + qoff;
                int o1 = __shfl(rof, e0 + 4, 64) + qoff;
                int o2 = __shfl(rof, e0 + 8, 64) + qoff;
                int o3 = __shfl(rof, e0 + 12, 64) + qoff;
                float mv0 = (e0 < cnt) ? 1.f : 0.f;
                float mv1 = (e0 + 4 < cnt) ? 1.f : 0.f;
                float mv2 = (e0 + 8 < cnt) ? 1.f : 0.f;
                float mv3 = (e0 + 12 < cnt) ? 1.f : 0.f;
                f32x2 m0 = {mv0, mv0}, m1 = {mv1, mv1}, m2 = {mv2, mv2}, m3 = {mv3, mv3};
                uint2 u0 = *(const uint2*)(h1c + (uint32_t)o0);
                uint2 u1 = *(const uint2*)(h1c + (uint32_t)o1);
                uint2 u2 = *(const uint2*)(h1c + (uint32_t)o2);
                uint2 u3 = *(const uint2*)(h1c + (uint32_t)o3);
                a0 += __builtin_amdgcn_cvt_pk_f32_fp8(u0.x, false) * m0;
                a1 += __builtin_amdgcn_cvt_pk_f32_fp8(u0.x, true) * m0;
                a2 += __builtin_amdgcn_cvt_pk_f32_fp8(u0.y, false) * m0;
                a3 += __builtin_amdgcn_cvt_pk_f32_fp8(u0.y, true) * m0;
                a0 += __builtin_amdgcn_cvt_pk_f32_fp8(u1.x, false) * m1;
                a1 += __builtin_amdgcn_cvt_pk_f32_fp8(u1.x, true) * m1;
                a2 += __builtin_amdgcn_cvt_pk_f32_fp8(u1.y, false) * m1;
                a3 += __builtin_amdgcn_cvt_pk_f32_fp8(u1.y, true) * m1;
                a0 += __builtin_amdgcn_cvt_pk_f32_fp8(u2.x, false) * m2;
                a1 += __builtin_amdgcn_cvt_pk_f32_fp8(u2.x, true) * m2;
                a2 += __builtin_amdgcn_cvt_pk_f32_fp8(u2.y, false) * m2;
                a3 += __builtin_amdgcn_cvt_pk_f32_fp8(u2.y, true) * m2;
                a0 += __builtin_amdgcn_cvt_pk_f32_fp8(u3.x, false) * m3;
                a1 += __builtin_amdgcn_cvt_pk_f32_fp8(u3.x, true) * m3;
                a2 += __builtin_amdgcn_cvt_pk_f32_fp8(u3.y, false) * m3;
                a3 += __builtin_amdgcn_cvt_pk_f32_fp8(u3.y, true) * m3;
            }
            i += cnt;
        }
        float ac[8] = {a0.x, a0.y, a1.x, a1.y, a2.x, a2.y, a3.x, a3.y};
        // fold the 4 edge-groups (lane bits 4,5)
#pragma unroll
        for (int j = 0; j < 8; ++j) {
            ac[j] += __shfl_xor(ac[j], 16, 64);
            ac[j] += __shfl_xor(ac[j], 32, 64);
        }
        if (lane < 16) {
            float sc = rs_in[w];
            float f0, f1;
            uint32_t o0, o1, o2, o3;
            f0 = fmaxf(fmaf(ac[0], sc, blo.x), 0.f); f1 = fmaxf(fmaf(ac[1], sc, blo.y), 0.f);
            o0 = (uint32_t)(unsigned short)f2bf(f0) | ((uint32_t)(unsigned short)f2bf(f1) << 16);
            f0 = fmaxf(fmaf(ac[2], sc, blo.z), 0.f); f1 = fmaxf(fmaf(ac[3], sc, blo.w), 0.f);
            o1 = (uint32_t)(unsigned short)f2bf(f0) | ((uint32_t)(unsigned short)f2bf(f1) << 16);
            f0 = fmaxf(fmaf(ac[4], sc, bhi.x), 0.f); f1 = fmaxf(fmaf(ac[5], sc, bhi.y), 0.f);
            o2 = (uint32_t)(unsigned short)f2bf(f0) | ((uint32_t)(unsigned short)f2bf(f1) << 16);
            f0 = fmaxf(fmaf(ac[6], sc, bhi.z), 0.f); f1 = fmaxf(fmaf(ac[7], sc, bhi.w), 0.f);
            o3 = (uint32_t)(unsigned short)f2bf(f0) | ((uint32_t)(unsigned short)f2bf(f1) << 16);
            int woff = (wv * 256 + ql * 16) ^ ((wv & 7) << 4);
            *(uint4*)((char*)x1s + woff) = make_uint4(o0, o1, o2, o3);
        }
    }
    __syncthreads();
    int vr = min(4, N - w_base);
    if (wv < 3) {
        // W2 fragments loaded here (after edge phase) to keep hot-loop VGPR pressure low
        short8 wf0 = *(const short8*)&Wg2[((wv * 4 + 0) * 64 + lane) * 8];
        short8 wf1 = *(const short8*)&Wg2[((wv * 4 + 1) * 64 + lane) * 8];
        short8 wf2 = *(const short8*)&Wg2[((wv * 4 + 2) * 64 + lane) * 8];
        short8 wf3 = *(const short8*)&Wg2[((wv * 4 + 3) * 64 + lane) * 8];
        int row = lane & 15, kc = lane >> 4;
        int rbase = row * 256 + kc * 16;
        int swz = (row & 7) << 4;
        f32x4 c = {};
        c = __builtin_amdgcn_mfma_f32_16x16x32_bf16(*(short8*)((char*)x1s + ((rbase + 0) ^ swz)),   wf0, c, 0, 0, 0);
        c = __builtin_amdgcn_mfma_f32_16x16x32_bf16(*(short8*)((char*)x1s + ((rbase + 64) ^ swz)),  wf1, c, 0, 0, 0);
        c = __builtin_amdgcn_mfma_f32_16x16x32_bf16(*(short8*)((char*)x1s + ((rbase + 128) ^ swz)), wf2, c, 0, 0, 0);
        c = __builtin_amdgcn_mfma_f32_16x16x32_bf16(*(short8*)((char*)x1s + ((rbase + 192) ^ swz)), wf3, c, 0, 0, 0);
        int cc = wv * 16 + row;     // output column 0..47 (only <40 valid)
        if (cc < OUT_DIM && kc == 0) {   // C rows 0..3 live in kc==0 lanes
            float s0 = rs_out[w_base + 0];
            float s1 = (vr > 1) ? rs_out[w_base + 1] : 0.f;
            float s2 = (vr > 2) ? rs_out[w_base + 2] : 0.f;
            float s3 = (vr > 3) ? rs_out[w_base + 3] : 0.f;
            int pk = __builtin_amdgcn_cvt_pk_fp8_f32(c[0] * s0, c[1] * s1, 0, false);
            pk = __builtin_amdgcn_cvt_pk_fp8_f32(c[2] * s2, c[3] * s3, pk, true);
            hs2[cc] = (uint32_t)pk;      // banks 0..15 per wave: conflict-free
        }
    }
    __syncthreads();
    if (t < 64) {                        // assemble padded 64B rows: dword d of row `node`
        int node = t >> 4, d = t & 15;
        uint32_t v = 0;
        if (d < 10) {
            int sh = node * 8;
            uint32_t b0 = (hs2[4 * d + 0] >> sh) & 0xffu;
            uint32_t b1 = (hs2[4 * d + 1] >> sh) & 0xffu;
            uint32_t b2 = (hs2[4 * d + 2] >> sh) & 0xffu;
            uint32_t b3 = (hs2[4 * d + 3] >> sh) & 0xffu;
            v = b0 | (b1 << 8) | (b2 << 16) | (b3 << 24);
        }
        if (node < vr) h2f[(size_t)(w_base + node) * 16 + d] = v;
    }
}

// ---------------- SpMM2 (fp8, 64B-padded rows) + bias + log_softmax ----------------
// 8 lanes/edge x uint2; 32 edges per it-step = 4 independent loads in flight; mask-free hot loop.
__global__ __launch_bounds__(256) void k_spmm2(const char* __restrict__ h2c, const int* __restrict__ rp,
                                               const int* __restrict__ col, const float* __restrict__ rs_in,
                                               const float* __restrict__ b2, float* __restrict__ out, int n) {
    int w = (blockIdx.x * 256 + threadIdx.x) >> 6;
    int lane = threadIdx.x & 63;
    if (w >= n) return;
    int grp = lane >> 3, fl = lane & 7;       // fl: feature-byte group (fl<5 real, 5..7 pad=0)
    int qoff = fl << 3;
    int s = rp[w], e = rp[w + 1];
    f32x2 a0 = {0.f, 0.f}, a1 = {0.f, 0.f}, a2 = {0.f, 0.f}, a3 = {0.f, 0.f};
    int i = s;
    while (i < e) {
        int cnt = min(64, e - i);
        int cl = (lane < cnt) ? lane : cnt - 1;
        int rof = col[i + cl] << 6;           // byte offset of 64B row
        int nfull = cnt & ~31;
        int it = 0;
        for (; it < nfull; it += 32) {        // mask-free full steps
            int o0 = __shfl(rof, it + grp, 64) + qoff;
            int o1 = __shfl(rof, it + 8 + grp, 64) + qoff;
            int o2 = __shfl(rof, it + 16 + grp, 64) + qoff;
            int o3 = __shfl(rof, it + 24 + grp, 64) + qoff;
            uint2 u0 = *(const uint2*)(h2c + (uint32_t)o0);
            uint2 u1 = *(const uint2*)(h2c + (uint32_t)o1);
            uint2 u2 = *(const uint2*)(h2c + (uint32_t)o2);
            uint2 u3 = *(const uint2*)(h2c + (uint32_t)o3);
            a0 += __builtin_amdgcn_cvt_pk_f32_fp8(u0.x, false);
            a1 += __builtin_amdgcn_cvt_pk_f32_fp8(u0.x, true);
            a2 += __builtin_amdgcn_cvt_pk_f32_fp8(u0.y, false);
            a3 += __builtin_amdgcn_cvt_pk_f32_fp8(u0.y, true);
            a0 += __builtin_amdgcn_cvt_pk_f32_fp8(u1.x, false);
            a1 += __builtin_amdgcn_cvt_pk_f32_fp8(u1.x, true);
            a2 += __builtin_amdgcn_cvt_pk_f32_fp8(u1.y, false);
            a3 += __builtin_amdgcn_cvt_pk_f32_fp8(u1.y, true);
            a0 += __builtin_amdgcn_cvt_pk_f32_fp8(u2.x, false);
            a1 += __builtin_amdgcn_cvt_pk_f32_fp8(u2.x, true);
            a2 += __builtin_amdgcn_cvt_pk_f32_fp8(u2.y, false);
            a3 += __builtin_amdgcn_cvt_pk_f32_fp8(u2.y, true);
            a0 += __builtin_amdgcn_cvt_pk_f32_fp8(u3.x, false);
            a1 += __builtin_amdgcn_cvt_pk_f32_fp8(u3.x, true);
            a2 += __builtin_amdgcn_cvt_pk_f32_fp8(u3.y, false);
            a3 += __builtin_amdgcn_cvt_pk_f32_fp8(u3.y, true);
        }
        if (it < cnt) {                       // one masked tail step (<=31 edges)
            int e0 = it + grp;                // e0+24 <= 63 always
            int o0 = __shfl(rof, e0, 64) + qoff;
            int o1 = __shfl(rof, e0 + 8, 64) + qoff;
            int o2 = __shfl(rof, e0 + 16, 64) + qoff;
            int o3 = __shfl(rof, e0 + 24, 64) + qoff;
            float mv0 = (e0 < cnt) ? 1.f : 0.f;
            float mv1 = (e0 + 8 < cnt) ? 1.f : 0.f;
            float mv2 = (e0 + 16 < cnt) ? 1.f : 0.f;
            float mv3 = (e0 + 24 < cnt) ? 1.f : 0.f;
            f32x2 m0 = {mv0, mv0}, m1 = {mv1, mv1}, m2 = {mv2, mv2}, m3 = {mv3, mv3};
            uint2 u0 = *(const uint2*)(h2c + (uint32_t)o0);
            uint2 u1 = *(const uint2*)(h2c + (uint32_t)o1);
            uint2 u2 = *(const uint2*)(h2c + (uint32_t)o2);
            uint2 u3 = *(const uint2*)(h2c + (uint32_t)o3);
            a0 += __builtin_amdgcn_cvt_pk_f32_fp8(u0.x, false) * m0;
            a1 += __builtin_amdgcn_cvt_pk_f32_fp8(u0.x, true) * m0;
            a2 += __builtin_amdgcn_cvt_pk_f32_fp8(u0.y, false) * m0;
            a3 += __builtin_amdgcn_cvt_pk_f32_fp8(u0.y, true) * m0;
            a0 += __builtin_amdgcn_cvt_pk_f32_fp8(u1.x, false) * m1;
            a1 += __builtin_amdgcn_cvt_pk_f32_fp8(u1.x, true) * m1;
            a2 += __builtin_amdgcn_cvt_pk_f32_fp8(u1.y, false) * m1;
            a3 += __builtin_amdgcn_cvt_pk_f32_fp8(u1.y, true) * m1;
            a0 += __builtin_amdgcn_cvt_pk_f32_fp8(u2.x, false) * m2;
            a1 += __builtin_amdgcn_cvt_pk_f32_fp8(u2.x, true) * m2;
            a2 += __builtin_amdgcn_cvt_pk_f32_fp8(u2.y, false) * m2;
            a3 += __builtin_amdgcn_cvt_pk_f32_fp8(u2.y, true) * m2;
            a0 += __builtin_amdgcn_cvt_pk_f32_fp8(u3.x, false) * m3;
            a1 += __builtin_amdgcn_cvt_pk_f32_fp8(u3.x, true) * m3;
            a2 += __builtin_amdgcn_cvt_pk_f32_fp8(u3.y, false) * m3;
            a3 += __builtin_amdgcn_cvt_pk_f32_fp8(u3.y, true) * m3;
        }
        i += cnt;
    }
    float ac[8] = {a0.x, a0.y, a1.x, a1.y, a2.x, a2.y, a3.x, a3.y};
    // fold 8 edge-groups (lane bits 3,4,5)
#pragma unroll
    for (int j = 0; j < 8; ++j) {
        ac[j] += __shfl_xor(ac[j], 8, 64);
        ac[j] += __shfl_xor(ac[j], 16, 64);
        ac[j] += __shfl_xor(ac[j], 32, 64);
    }
    bool act = lane < 5;
    float sc = rs_in[w];
    int bb = (fl < 5) ? fl * 8 : 0;           // guard b2 OOB for pad lanes
    float val[8];
#pragma unroll
    for (int j = 0; j < 8; ++j)
        val[j] = fmaf(ac[j], sc, b2[bb + j]);
    float pm = -INFINITY;
    if (act) {
        pm = val[0];
#pragma unroll
        for (int j = 1; j < 8; ++j) pm = fmaxf(pm, val[j]);
    }
    pm = fmaxf(pm, __shfl_xor(pm, 4, 8));
    pm = fmaxf(pm, __shfl_xor(pm, 2, 8));
    pm = fmaxf(pm, __shfl_xor(pm, 1, 8));
    float ex = 0.f;
    if (act) {
#pragma unroll
        for (int j = 0; j < 8; ++j) ex += expf(val[j] - pm);
    }
    ex += __shfl_xor(ex, 4, 8);
    ex += __shfl_xor(ex, 2, 8);
    ex += __shfl_xor(ex, 1, 8);
    if (act) {
        float l = pm + logf(ex);
        float4 o0 = {val[0] - l, val[1] - l, val[2] - l, val[3] - l};
        float4 o1 = {val[4] - l, val[5] - l, val[6] - l, val[7] - l};
        float* op = out + (size_t)w * OUT_DIM + lane * 8;
        *(float4*)op = o0;
        *(float4*)(op + 4) = o1;
    }
}

// ---------------- launch ----------------

extern "C" void kernel_launch(void* const* d_in, const int* in_sizes, int n_in,
                              void* d_out, int out_size, void* d_ws, size_t ws_size,
                              hipStream_t stream) {
    const int N = in_sizes[0] / IN_DIM;
    const int E = in_sizes[5];
    const float* h  = (const float*)d_in[0];
    const float* W1 = (const float*)d_in[1];
    const float* b1 = (const float*)d_in[2];
    const float* W2 = (const float*)d_in[3];
    const float* b2 = (const float*)d_in[4];
    const int* src  = (const int*)d_in[5];
    const int* dst  = (const int*)d_in[6];
    float* out = (float*)d_out;

    const int NBINS  = (N + BIN_SIZE - 1) >> BIN_SHIFT;   // 98
    const int NCHUNK = (E + CHUNK - 1) / CHUNK;           // 391

    char* w = (char*)d_ws;
    size_t off = 0;
    auto alloc = [&](size_t bytes) -> void* {
        void* p = w + off;
        off += (bytes + 255) & ~(size_t)255;
        return p;
    };
    int* deg_in   = (int*)alloc((size_t)N * 4);
    int* deg_out  = (int*)alloc((size_t)N * 4);
    int* row_ptr  = (int*)alloc((size_t)(N + 1) * 4);
    int* cursor   = (int*)alloc((size_t)N * 4);
    int* bsum     = (int*)alloc(1024 * 4);
    float* rs_out = (float*)alloc((size_t)N * 4);
    float* rs_in  = (float*)alloc((size_t)N * 4);
    int* col      = (int*)alloc((size_t)E * 4);
    int* bboD     = (int*)alloc((size_t)NCHUNK * (NBINS + 1) * 4);
    int* bboS     = (int*)alloc((size_t)NCHUNK * (NBINS + 1) * 4);
    short* Wg     = (short*)alloc((size_t)8 * 8 * 64 * 8 * 2);    // 64 KB
    short* Wg2    = (short*)alloc((size_t)3 * 4 * 64 * 8 * 2);    // 12 KB
    float* b1p    = (float*)alloc((size_t)HID * 4);
    int* hsave    = (int*)alloc((size_t)NBINS * GSPLIT * BIN_SIZE * 4);   // 3.2 MB
    // staging regions; dead before their aliases are written (stream-ordered):
    //   stD read last by k_col, then k_gemm1 writes h1f over it.
    //   stS read last by k_deg (src pass), then k_spmm1f writes h2f over it.
    size_t stD_bytes = (size_t)E * 4;  if ((size_t)N * HID > stD_bytes) stD_bytes = (size_t)N * HID;
    size_t stS_bytes = (size_t)E * 2;  if ((size_t)N * 64 > stS_bytes) stS_bytes = (size_t)N * 64;
    uint32_t* stD = (uint32_t*)alloc(stD_bytes);
    unsigned short* stS = (unsigned short*)alloc(stS_bytes);
    uint32_t* h1f = (uint32_t*)stD;                       // fp8 [N][128], 12.8 MB
    uint32_t* h2f = (uint32_t*)stS;                       // fp8 [N][64] (40 real + 24 pad), 6.4 MB

    int gN = (N + 255) / 256;
    int NB = (N + 1023) / 1024;
    int Z = (N + 3) / 4;
    int setup_units = 8192 + 3 * 4 * 64 * 8 + HID + 2 * Z;
    int gsetup = (setup_units + 255) / 256;

    k_setup<<<gsetup, 256, 0, stream>>>(W1, W2, b1, Wg, Wg2, b1p, deg_in, deg_out, Z);
    k_binscatter<<<NCHUNK, 256, 0, stream>>>(src, dst, stD, stS, bboD, bboS, E, NBINS);
    k_deg<<<dim3(NBINS, GSPLIT, 2), 256, 0, stream>>>(stD, bboD, stS, bboS, deg_in, deg_out, hsave, NCHUNK, NBINS);
    k_scan1<<<NB, 256, 0, stream>>>(deg_in, row_ptr, bsum, rs_in, N);
    k_scan2<<<1, 1024, 0, stream>>>(bsum, NB);
    k_scan3<<<gN, 256, 0, stream>>>(row_ptr, bsum, cursor, deg_out, rs_out, N, E);
    k_col<<<dim3(NBINS, GSPLIT), 256, 0, stream>>>(stD, bboD, hsave, cursor, col, N, NCHUNK, NBINS);
    k_gemm1<<<(N + 63) / 64, 256, 0, stream>>>(h, Wg, rs_out, h1f, N);
    k_spmm1f<<<(N + 3) / 4, 256, 0, stream>>>((const char*)h1f, row_ptr, col, rs_in, rs_out, b1p, Wg2, h2f, N);
    k_spmm2<<<(N + 3) / 4, 256, 0, stream>>>((const char*)h2f, row_ptr, col, rs_in, b2, out, N);
}